// Round 4
// baseline (435.436 us; speedup 1.0000x reference)
//
#include <hip/hip_runtime.h>
#include <hip/hip_bf16.h>

#define NN 100000
#define EE 1250000

#define RL(x, l) __builtin_amdgcn_readlane((x), (l))
#define RLF(x, l) __int_as_float(__builtin_amdgcn_readlane(__float_as_int(x), (l)))

typedef __attribute__((ext_vector_type(8))) short v8s;
typedef __attribute__((ext_vector_type(4))) float v4f;
typedef __attribute__((ext_vector_type(4))) unsigned int v4u;

__device__ __forceinline__ unsigned short bf16rtn(float x) {
    unsigned u = __float_as_uint(x);
    unsigned r = u + 0x7fffu + ((u >> 16) & 1u);
    return (unsigned short)(r >> 16);
}
__device__ __forceinline__ unsigned bf16rtn2(float lo, float hi) {
    return (unsigned)bf16rtn(lo) | ((unsigned)bf16rtn(hi) << 16);
}
__device__ __forceinline__ float bflo(unsigned u) { return __uint_as_float(u << 16); }
__device__ __forceinline__ float bfhi(unsigned u) { return __uint_as_float(u & 0xffff0000u); }
__device__ __forceinline__ float bfs(unsigned short s) { return __uint_as_float((unsigned)s << 16); }

// ---------------- CSR build (packed; R9-proven) ----------------
// Atomic pass: ~23 G returning atomics/s fabric ceiling (R2/R5/R9/R10), ~50us
// floor. Padded rows (R10) and counter padding (R7) both null/regressions.

__global__ __launch_bounds__(256) void k_count(const int* __restrict__ ei,
                                               int* __restrict__ cnt,
                                               int* __restrict__ slot) {
    int e = blockIdx.x * 256 + threadIdx.x;
    if (e >= EE) return;
    int d = __builtin_nontemporal_load(&ei[EE + e]);
    int s = atomicAdd(&cnt[d], 1);
    __builtin_nontemporal_store(s, &slot[e]);
}

__global__ __launch_bounds__(256) void k_bsum(const int* __restrict__ cnt, int* __restrict__ bsum) {
    __shared__ int ls[256];
    int b = blockIdx.x, tid = threadIdx.x;
    int base = b * 1024 + tid * 4;
    int s = 0;
    #pragma unroll
    for (int j = 0; j < 4; ++j) { int g = base + j; if (g < NN) s += cnt[g]; }
    ls[tid] = s; __syncthreads();
    for (int off = 128; off > 0; off >>= 1) {
        if (tid < off) ls[tid] += ls[tid + off];
        __syncthreads();
    }
    if (tid == 0) bsum[b] = ls[0];
}

// per-1024 scan; block base computed in-kernel from bsum
__global__ __launch_bounds__(256) void k_scan_out(const int* __restrict__ cnt,
                                                  const int* __restrict__ bsum,
                                                  int* __restrict__ rowptr) {
    __shared__ int ls[256];
    __shared__ int sbase;
    int b = blockIdx.x, tid = threadIdx.x;
    if (tid < 64) {
        int w0 = (tid < b) ? bsum[tid] : 0;
        int w1 = ((64 + tid) < b) ? bsum[64 + tid] : 0;
        int s = w0 + w1;
        #pragma unroll
        for (int m = 32; m >= 1; m >>= 1) s += __shfl_xor(s, m, 64);
        if (tid == 0) sbase = s;
    }
    int base = b * 1024 + tid * 4;
    int c[4]; int s = 0;
    #pragma unroll
    for (int j = 0; j < 4; ++j) {
        int g = base + j;
        c[j] = (g < NN) ? cnt[g] : 0;
        s += c[j];
    }
    ls[tid] = s; __syncthreads();
    for (int off = 1; off < 256; off <<= 1) {
        int v = (tid >= off) ? ls[tid - off] : 0;
        __syncthreads();
        ls[tid] += v;
        __syncthreads();
    }
    int excl = ls[tid] - s + sbase;
    #pragma unroll
    for (int j = 0; j < 4; ++j) {
        int g = base + j;
        if (g < NN) {
            rowptr[g + 1] = excl + c[j];
            excl += c[j];
        }
    }
    if (b == 0 && tid == 0) rowptr[0] = 0;
}

__global__ __launch_bounds__(256) void k_fill(const int* __restrict__ ei,
                                              const float* __restrict__ ew,
                                              const int* __restrict__ slot,
                                              const int* __restrict__ rowptr,
                                              int2* __restrict__ epair) {
    int e = blockIdx.x * 256 + threadIdx.x;
    if (e >= EE) return;
    int s = __builtin_nontemporal_load(&ei[e]);
    int d = __builtin_nontemporal_load(&ei[EE + e]);
    float w = __builtin_nontemporal_load(&ew[e]);
    int sl = __builtin_nontemporal_load(&slot[e]);
    int p = rowptr[d] + sl;
    epair[p] = make_int2(s, __float_as_int(w));
}

// deg[n] = 1 + sum_row ew -> dinv[n], xd[n] = dinv[n]*x[n].  4 nodes/wave.
__global__ __launch_bounds__(256) void k_deg(const int* __restrict__ rowptr,
                                             const int2* __restrict__ epair,
                                             const float* __restrict__ x,
                                             float* __restrict__ dinv,
                                             float* __restrict__ xd) {
    int lane = threadIdx.x & 63;
    int wid  = threadIdx.x >> 6;
    int l16  = lane & 15;
    int sub  = lane >> 4;
    int node = (blockIdx.x * 4 + wid) * 4 + sub;
    if (node >= NN) return;
    int beg = rowptr[node], end = rowptr[node + 1];
    float s = 0.f;
    for (int idx = beg + l16; idx < end; idx += 16)
        s += __int_as_float(epair[idx].y);
    #pragma unroll
    for (int m = 8; m >= 1; m >>= 1) s += __shfl_xor(s, m, 64);
    if (l16 == 0) {
        float di = rsqrtf(s + 1.0f);
        dinv[node] = di;
        xd[node] = di * x[node];
    }
}

// ---------------- W pre-pack for MFMA (R12, R13-fixed) ----------------
// Packs a 64x64 row-major fp32 W into mfma_f32_16x16x32_bf16 B-fragment
// order, SPLIT hi+lo bf16 (Whi + Wlo reconstructs W to ~2^-17 rel => fp32-
// equivalent W precision; only the activation v carries bf16 rounding).
// Fragment (h, kt, nt): lane l holds 8 bf16 = W[kt*32 + (l>>4)*8 + j]
// [nt*16 + (l&15)], j=0..7, packed k-pairs per dword.  Group index
// g = (h*2+kt)*4+nt; dword addr = (g*64 + l)*4 + d.  16 KB per W.
// R13 BUGFIX: slot loop is 512 entries (i<2), NOT 1024.
// grid = 4 blocks: {W3, W4, W5, fW1}.
__global__ __launch_bounds__(256) void k_wpk(const float* __restrict__ Wa,
                                             const float* __restrict__ Wb,
                                             const float* __restrict__ Wc,
                                             const float* __restrict__ Wd,
                                             unsigned* __restrict__ Wf) {
    const float* W = (blockIdx.x == 0) ? Wa : (blockIdx.x == 1) ? Wb
                   : (blockIdx.x == 2) ? Wc : Wd;
    unsigned* out = Wf + blockIdx.x * 4096;
    int t = threadIdx.x;
    #pragma unroll
    for (int i = 0; i < 2; ++i) {
        int s = t * 2 + i;               // slot 0..511 = (kt*4+nt)*64 + lane
        int lane = s & 63;
        int nt = (s >> 6) & 3;
        int kt = s >> 8;                 // 0..1
        int col = nt * 16 + (lane & 15);
        int k0 = kt * 32 + (lane >> 4) * 8;
        unsigned hi[4], lo[4];
        #pragma unroll
        for (int d = 0; d < 4; ++d) {
            float w0 = W[(k0 + 2 * d) * 64 + col];
            float w1 = W[(k0 + 2 * d + 1) * 64 + col];
            unsigned short h0 = bf16rtn(w0), h1 = bf16rtn(w1);
            float r0 = w0 - bfs(h0), r1 = w1 - bfs(h1);
            hi[d] = (unsigned)h0 | ((unsigned)h1 << 16);
            lo[d] = (unsigned)bf16rtn(r0) | ((unsigned)bf16rtn(r1) << 16);
        }
        int gh = (0 * 2 + kt) * 4 + nt;  // 0..7
        int gl = (1 * 2 + kt) * 4 + nt;  // 8..15
        *(v4u*)&out[(gh * 64 + lane) * 4] = (v4u){hi[0], hi[1], hi[2], hi[3]};
        *(v4u*)&out[(gl * 64 + lane) * 4] = (v4u){lo[0], lo[1], lo[2], lo[3]};
    }
}

// ---------------- Dual-node interleaved gather (R14) ----------------
// Latency-bound fix: R13's sequential 4-node loop had only 8 row-loads in
// flight per wave (vmcnt(0) join at each node). Interleave node PAIRS:
// issue A's 8 loads, B's 8 loads, then A's fmas (vmcnt(8) -> B stays in
// flight), then B's. 16 loads in flight per wave; per-node fma order is
// unchanged -> bit-identical accumulation.
__device__ __forceinline__ void gather2(
    const unsigned* __restrict__ G16, const int2* __restrict__ ep,
    int begA, int endA, int begB, int endB, int lc, int half,
    float& axA, float& ayA, float& axB, float& ayB)
{
    int jA = begA, jB = begB;
    // paired full batches
    while (jA + 16 <= endA && jB + 16 <= endB) {
        unsigned uA[8], uB[8]; float nA[8], nB[8];
        #pragma unroll
        for (int t = 0; t < 8; ++t) {
            int2 pa = ep[jA + t];             // uniform -> s_load
            int2 pb = ep[jA + 8 + t];
            int src = half ? pb.x : pa.x;
            nA[t] = __int_as_float(half ? pb.y : pa.y);
            uA[t] = G16[src * 32 + lc];
        }
        #pragma unroll
        for (int t = 0; t < 8; ++t) {
            int2 pa = ep[jB + t];
            int2 pb = ep[jB + 8 + t];
            int src = half ? pb.x : pa.x;
            nB[t] = __int_as_float(half ? pb.y : pa.y);
            uB[t] = G16[src * 32 + lc];
        }
        #pragma unroll
        for (int t = 0; t < 8; ++t) {
            axA = fmaf(bflo(uA[t]), nA[t], axA);
            ayA = fmaf(bfhi(uA[t]), nA[t], ayA);
        }
        #pragma unroll
        for (int t = 0; t < 8; ++t) {
            axB = fmaf(bflo(uB[t]), nB[t], axB);
            ayB = fmaf(bfhi(uB[t]), nB[t], ayB);
        }
        jA += 16; jB += 16;
    }
    // leftover full batches (one side only; rare: |degA-degB| > 16)
    while (jA + 16 <= endA) {
        unsigned u[8]; float nv[8];
        #pragma unroll
        for (int t = 0; t < 8; ++t) {
            int2 pa = ep[jA + t];
            int2 pb = ep[jA + 8 + t];
            int src = half ? pb.x : pa.x;
            nv[t] = __int_as_float(half ? pb.y : pa.y);
            u[t] = G16[src * 32 + lc];
        }
        #pragma unroll
        for (int t = 0; t < 8; ++t) {
            axA = fmaf(bflo(u[t]), nv[t], axA);
            ayA = fmaf(bfhi(u[t]), nv[t], ayA);
        }
        jA += 16;
    }
    while (jB + 16 <= endB) {
        unsigned u[8]; float nv[8];
        #pragma unroll
        for (int t = 0; t < 8; ++t) {
            int2 pa = ep[jB + t];
            int2 pb = ep[jB + 8 + t];
            int src = half ? pb.x : pa.x;
            nv[t] = __int_as_float(half ? pb.y : pa.y);
            u[t] = G16[src * 32 + lc];
        }
        #pragma unroll
        for (int t = 0; t < 8; ++t) {
            axB = fmaf(bflo(u[t]), nv[t], axB);
            ayB = fmaf(bfhi(u[t]), nv[t], ayB);
        }
        jB += 16;
    }
    // paired masked tails (1..15 edges each; the common case at deg~12.5)
    bool tA = jA < endA, tB = jB < endB;
    if (tA | tB) {
        unsigned uA[8], uB[8]; float nA[8], nB[8];
        if (tA) {
            #pragma unroll
            for (int t = 0; t < 8; ++t) {
                int ia = jA + t, ib = jA + 8 + t;   // uniform
                int2 pa = ep[ia < endA ? ia : jA];
                int2 pb = ep[ib < endA ? ib : jA];
                int src = half ? pb.x : pa.x;
                float w = __int_as_float(half ? pb.y : pa.y);
                bool v = half ? (ib < endA) : (ia < endA);
                nA[t] = v ? w : 0.f;
                uA[t] = G16[src * 32 + lc];
            }
        }
        if (tB) {
            #pragma unroll
            for (int t = 0; t < 8; ++t) {
                int ia = jB + t, ib = jB + 8 + t;
                int2 pa = ep[ia < endB ? ia : jB];
                int2 pb = ep[ib < endB ? ib : jB];
                int src = half ? pb.x : pa.x;
                float w = __int_as_float(half ? pb.y : pa.y);
                bool v = half ? (ib < endB) : (ia < endB);
                nB[t] = v ? w : 0.f;
                uB[t] = G16[src * 32 + lc];
            }
        }
        if (tA) {
            #pragma unroll
            for (int t = 0; t < 8; ++t) {
                axA = fmaf(bflo(uA[t]), nA[t], axA);
                ayA = fmaf(bfhi(uA[t]), nA[t], ayA);
            }
        }
        if (tB) {
            #pragma unroll
            for (int t = 0; t < 8; ++t) {
                axB = fmaf(bflo(uB[t]), nB[t], axB);
                ayB = fmaf(bfhi(uB[t]), nB[t], ayB);
            }
        }
    }
}

// ---------------- Layers ----------------
// Identity: Agg_l[d] = dinv_d * ( G'_l[d] + sum_e w_e * G'_l[src] ), G' = dinv (.) G.
// G' stored bf16 (rows = 32 uints = 128 B). All accumulation fp32.
// R12/R13: matvec on the MFMA pipe. R14: dual-node interleaved gather.

// Layer 1: z scalar agg + matvec, W2 via LDS. grid NN/16.
__global__ __launch_bounds__(256) void k_l1(
    const float* __restrict__ xd, const float* __restrict__ dinv,
    const int* __restrict__ rowptr, const int2* __restrict__ ep,
    const float* __restrict__ W1, const float* __restrict__ b1,
    const float* __restrict__ W2, unsigned short* __restrict__ Gout)
{
    __shared__ float sW[4096];
    int tid = threadIdx.x;
    #pragma unroll
    for (int i = 0; i < 16; ++i) sW[tid + i * 256] = W2[tid + i * 256];
    __syncthreads();
    int lane = tid & 63, l16 = lane & 15, sub = lane >> 4;
    int g4 = blockIdx.x * 4 + (tid >> 6);
    int nodeS = g4 * 4 + sub;
    int beg = rowptr[nodeS], end = rowptr[nodeS + 1];
    float partial = 0.f;
    for (int idx = beg + l16; idx < end; idx += 16) {
        int2 p = ep[idx];
        partial = fmaf(__int_as_float(p.y), xd[p.x], partial);
    }
    #pragma unroll
    for (int m = 8; m >= 1; m >>= 1) partial += __shfl_xor(partial, m, 64);
    float z = dinv[nodeS] * (xd[nodeS] + partial);   // valid where l16==0
    float z0 = RLF(z, 0), z1 = RLF(z, 16), z2 = RLF(z, 32), z3 = RLF(z, 48);
    float w1l = W1[lane], b1l = b1[lane];
    float v0 = fmaxf(fmaf(z0, w1l, b1l), 0.f);
    float v1 = fmaxf(fmaf(z1, w1l, b1l), 0.f);
    float v2 = fmaxf(fmaf(z2, w1l, b1l), 0.f);
    float v3 = fmaxf(fmaf(z3, w1l, b1l), 0.f);
    float a0 = 0.f, a1 = 0.f, a2 = 0.f, a3 = 0.f;
    #pragma unroll
    for (int k = 0; k < 64; ++k) {
        float wk = sW[k * 64 + lane];
        a0 = fmaf(RLF(v0, k), wk, a0);
        a1 = fmaf(RLF(v1, k), wk, a1);
        a2 = fmaf(RLF(v2, k), wk, a2);
        a3 = fmaf(RLF(v3, k), wk, a3);
    }
    int n0 = g4 * 4;
    Gout[(n0 + 0) * 64 + lane] = bf16rtn(dinv[n0 + 0] * a0);
    Gout[(n0 + 1) * 64 + lane] = bf16rtn(dinv[n0 + 1] * a1);
    Gout[(n0 + 2) * 64 + lane] = bf16rtn(dinv[n0 + 2] * a2);
    Gout[(n0 + 3) * 64 + lane] = bf16rtn(dinv[n0 + 3] * a3);
}

// Fused gather + bias/relu + MFMA matvec + dinv scale (layers 2..4).
// 4 nodes/wave, pair-interleaved gather; grid = NN/16.
__global__ __launch_bounds__(256) void k_gmv(
    const unsigned* __restrict__ G16, const float* __restrict__ dinv,
    const int* __restrict__ rowptr, const int2* __restrict__ ep,
    const float* __restrict__ bias, const unsigned* __restrict__ Wf,
    unsigned short* __restrict__ Gout)
{
    __shared__ __align__(16) unsigned sB[4096];   // 16 KB: Whi/Wlo fragments
    __shared__ __align__(16) unsigned sA[4][128]; // per-wave A scratch (4n x 32dw)
    int tid = threadIdx.x;
    #pragma unroll
    for (int i = 0; i < 4; ++i)
        ((v4u*)sB)[tid + i * 256] = ((const v4u*)Wf)[tid + i * 256];
    int lane = tid & 63;
    int wid  = tid >> 6;
    int lc   = lane & 31;
    int half = lane >> 5;
    int n0 = (blockIdx.x * 4 + wid) * 4;
    float2 bb = ((const float2*)bias)[lc];        // (b[2lc], b[2lc+1])
    // ---- gather 4 nodes as 2 interleaved pairs, pack v rows into sA ----
    #pragma unroll
    for (int rp = 0; rp < 2; ++rp) {
        int nodeA = n0 + rp * 2, nodeB = nodeA + 1;
        int begA = __builtin_amdgcn_readfirstlane(rowptr[nodeA]);
        int endA = __builtin_amdgcn_readfirstlane(rowptr[nodeA + 1]);
        int begB = __builtin_amdgcn_readfirstlane(rowptr[nodeB]);
        int endB = __builtin_amdgcn_readfirstlane(rowptr[nodeB + 1]);
        float axA = 0.f, ayA = 0.f, axB = 0.f, ayB = 0.f;
        if (half == 0) {
            unsigned ua = G16[nodeA * 32 + lc];
            unsigned ub = G16[nodeB * 32 + lc];
            axA = bflo(ua); ayA = bfhi(ua);
            axB = bflo(ub); ayB = bfhi(ub);
        }
        gather2(G16, ep, begA, endA, begB, endB, lc, half, axA, ayA, axB, ayB);
        axA += __shfl_xor(axA, 32, 64);           // both halves hold full sums
        ayA += __shfl_xor(ayA, 32, 64);
        axB += __shfl_xor(axB, 32, 64);
        ayB += __shfl_xor(ayB, 32, 64);
        float dA = dinv[nodeA], dB = dinv[nodeB];
        float veA = fmaxf(fmaf(dA, axA, bb.x), 0.f);
        float voA = fmaxf(fmaf(dA, ayA, bb.y), 0.f);
        float veB = fmaxf(fmaf(dB, axB, bb.x), 0.f);
        float voB = fmaxf(fmaf(dB, ayB, bb.y), 0.f);
        if (half == 0) {
            sA[wid][(rp * 2 + 0) * 32 + lc] = bf16rtn2(veA, voA);
            sA[wid][(rp * 2 + 1) * 32 + lc] = bf16rtn2(veB, voB);
        }
    }
    __syncthreads();                              // sB ready (sA is wave-local)
    // ---- matvec on MFMA pipe ----
    int rr  = lane & 3;                           // A row (rows 4-15 = dup, unused)
    int blk = lane >> 4;
    v8s a0 = *(const v8s*)&sA[wid][rr * 32 +  0 + blk * 4];   // kt=0
    v8s a1 = *(const v8s*)&sA[wid][rr * 32 + 16 + blk * 4];   // kt=1
    v4f acc[4];
    #pragma unroll
    for (int nt = 0; nt < 4; ++nt) {
        v8s bh0 = *(const v8s*)&sB[((0 * 4 + nt) * 64 + lane) * 4];  // h=0 kt=0
        v8s bh1 = *(const v8s*)&sB[((1 * 4 + nt) * 64 + lane) * 4];  // h=0 kt=1
        v8s bl0 = *(const v8s*)&sB[((2 * 4 + nt) * 64 + lane) * 4];  // h=1 kt=0
        v8s bl1 = *(const v8s*)&sB[((3 * 4 + nt) * 64 + lane) * 4];  // h=1 kt=1
        v4f c = {0.f, 0.f, 0.f, 0.f};
        c = __builtin_amdgcn_mfma_f32_16x16x32_bf16(a0, bl0, c, 0, 0, 0);
        c = __builtin_amdgcn_mfma_f32_16x16x32_bf16(a1, bl1, c, 0, 0, 0);
        c = __builtin_amdgcn_mfma_f32_16x16x32_bf16(a0, bh0, c, 0, 0, 0);
        c = __builtin_amdgcn_mfma_f32_16x16x32_bf16(a1, bh1, c, 0, 0, 0);
        acc[nt] = c;
    }
    // lanes 0-15: acc[nt][r] = node n0+r, feature nt*16+lane
    if (lane < 16) {
        float4 dn = *(const float4*)&dinv[n0];
        #pragma unroll
        for (int r = 0; r < 4; ++r) {
            float d = (r == 0) ? dn.x : (r == 1) ? dn.y : (r == 2) ? dn.z : dn.w;
            #pragma unroll
            for (int nt = 0; nt < 4; ++nt)
                Gout[(n0 + r) * 64 + nt * 16 + lane] = bf16rtn(d * acc[nt][r]);
        }
    }
}

// Fused gather + layer-5 bias/relu + head (fW1 MFMA matvec, relu, fW2 dot).
// Same pair-interleaved 4-node structure; grid = NN/16.
__global__ __launch_bounds__(256) void k_ghead(
    const unsigned* __restrict__ G16, const float* __restrict__ dinv,
    const int* __restrict__ rowptr, const int2* __restrict__ ep,
    const float* __restrict__ b5, const unsigned* __restrict__ Wf,
    const float* __restrict__ fb1, const float* __restrict__ fW2,
    const float* __restrict__ fb2, float* __restrict__ out)
{
    __shared__ __align__(16) unsigned sB[4096];
    __shared__ __align__(16) unsigned sA[4][128];
    int tid = threadIdx.x;
    #pragma unroll
    for (int i = 0; i < 4; ++i)
        ((v4u*)sB)[tid + i * 256] = ((const v4u*)Wf)[tid + i * 256];
    int lane = tid & 63;
    int wid  = tid >> 6;
    int lc   = lane & 31;
    int half = lane >> 5;
    int n0 = (blockIdx.x * 4 + wid) * 4;
    float2 bb = ((const float2*)b5)[lc];
    int l16 = lane & 15;
    float fb1v[4], fw2v[4];
    #pragma unroll
    for (int nt = 0; nt < 4; ++nt) {
        fb1v[nt] = fb1[nt * 16 + l16];
        fw2v[nt] = fW2[nt * 16 + l16];
    }
    float fb2s = fb2[0];
    #pragma unroll
    for (int rp = 0; rp < 2; ++rp) {
        int nodeA = n0 + rp * 2, nodeB = nodeA + 1;
        int begA = __builtin_amdgcn_readfirstlane(rowptr[nodeA]);
        int endA = __builtin_amdgcn_readfirstlane(rowptr[nodeA + 1]);
        int begB = __builtin_amdgcn_readfirstlane(rowptr[nodeB]);
        int endB = __builtin_amdgcn_readfirstlane(rowptr[nodeB + 1]);
        float axA = 0.f, ayA = 0.f, axB = 0.f, ayB = 0.f;
        if (half == 0) {
            unsigned ua = G16[nodeA * 32 + lc];
            unsigned ub = G16[nodeB * 32 + lc];
            axA = bflo(ua); ayA = bfhi(ua);
            axB = bflo(ub); ayB = bfhi(ub);
        }
        gather2(G16, ep, begA, endA, begB, endB, lc, half, axA, ayA, axB, ayB);
        axA += __shfl_xor(axA, 32, 64);
        ayA += __shfl_xor(ayA, 32, 64);
        axB += __shfl_xor(axB, 32, 64);
        ayB += __shfl_xor(ayB, 32, 64);
        float dA = dinv[nodeA], dB = dinv[nodeB];
        float veA = fmaxf(fmaf(dA, axA, bb.x), 0.f);
        float voA = fmaxf(fmaf(dA, ayA, bb.y), 0.f);
        float veB = fmaxf(fmaf(dB, axB, bb.x), 0.f);
        float voB = fmaxf(fmaf(dB, ayB, bb.y), 0.f);
        if (half == 0) {
            sA[wid][(rp * 2 + 0) * 32 + lc] = bf16rtn2(veA, voA);
            sA[wid][(rp * 2 + 1) * 32 + lc] = bf16rtn2(veB, voB);
        }
    }
    __syncthreads();
    int rr  = lane & 3;
    int blk = lane >> 4;
    v8s a0 = *(const v8s*)&sA[wid][rr * 32 +  0 + blk * 4];
    v8s a1 = *(const v8s*)&sA[wid][rr * 32 + 16 + blk * 4];
    v4f acc[4];
    #pragma unroll
    for (int nt = 0; nt < 4; ++nt) {
        v8s bh0 = *(const v8s*)&sB[((0 * 4 + nt) * 64 + lane) * 4];
        v8s bh1 = *(const v8s*)&sB[((1 * 4 + nt) * 64 + lane) * 4];
        v8s bl0 = *(const v8s*)&sB[((2 * 4 + nt) * 64 + lane) * 4];
        v8s bl1 = *(const v8s*)&sB[((3 * 4 + nt) * 64 + lane) * 4];
        v4f c = {0.f, 0.f, 0.f, 0.f};
        c = __builtin_amdgcn_mfma_f32_16x16x32_bf16(a0, bl0, c, 0, 0, 0);
        c = __builtin_amdgcn_mfma_f32_16x16x32_bf16(a1, bl1, c, 0, 0, 0);
        c = __builtin_amdgcn_mfma_f32_16x16x32_bf16(a0, bh0, c, 0, 0, 0);
        c = __builtin_amdgcn_mfma_f32_16x16x32_bf16(a1, bh1, c, 0, 0, 0);
        acc[nt] = c;
    }
    // all lanes hold a dup copy: lane l, reg r -> node n0+r, col l&15
    float tr[4];
    #pragma unroll
    for (int r = 0; r < 4; ++r) {
        float t = 0.f;
        #pragma unroll
        for (int nt = 0; nt < 4; ++nt)
            t += fmaxf(acc[nt][r] + fb1v[nt], 0.f) * fw2v[nt];
        #pragma unroll
        for (int m = 8; m >= 1; m >>= 1) t += __shfl_xor(t, m, 64);
        tr[r] = t;
    }
    if (lane == 0) {
        float4 o = {tr[0] + fb2s, tr[1] + fb2s, tr[2] + fb2s, tr[3] + fb2s};
        *(float4*)&out[n0] = o;
    }
}

// ---------------- Launch ----------------

extern "C" void kernel_launch(void* const* d_in, const int* in_sizes, int n_in,
                              void* d_out, int out_size, void* d_ws, size_t ws_size,
                              hipStream_t stream) {
    const float* x   = (const float*)d_in[0];
    const int*   ei  = (const int*)d_in[1];
    const float* ew  = (const float*)d_in[2];
    const float* W1  = (const float*)d_in[3];
    const float* b1  = (const float*)d_in[4];
    const float* W2  = (const float*)d_in[5];
    const float* b2  = (const float*)d_in[6];
    const float* W3  = (const float*)d_in[7];
    const float* b3  = (const float*)d_in[8];
    const float* W4  = (const float*)d_in[9];
    const float* b4  = (const float*)d_in[10];
    const float* W5  = (const float*)d_in[11];
    const float* b5  = (const float*)d_in[12];
    const float* fW1 = (const float*)d_in[13];
    const float* fb1 = (const float*)d_in[14];
    const float* fW2 = (const float*)d_in[15];
    const float* fb2 = (const float*)d_in[16];
    float* out = (float*)d_out;

    char* ws = (char*)d_ws;
    size_t o = 0;
    auto alloc = [&](size_t elems) -> void* {
        void* p = (void*)(ws + o);
        o += ((elems * 4 + 255) / 256) * 256;
        return p;
    };
    float* dinv   = (float*)alloc(NN);
    float* xd     = (float*)alloc(NN);
    int*   rowptr = (int*)alloc(NN + 1);
    int*   cnt    = (int*)alloc(NN);
    int*   bsum   = (int*)alloc(128);
    int2*  epair  = (int2*)alloc(2 * (size_t)EE);
    unsigned* Ga16 = (unsigned*)alloc((size_t)NN * 32);   // bf16 feature rows
    unsigned* Gb16 = (unsigned*)alloc((size_t)NN * 32);
    int*   slot   = (int*)alloc(EE);
    unsigned* Wf  = (unsigned*)alloc(4 * 4096);           // pre-packed W frags

    int gE  = (EE + 255) / 256;
    int nb  = (NN + 1023) / 1024;    // 98
    int gW4 = NN / 16;               // 6250: 4 waves x 4 nodes per block

    k_wpk<<<4, 256, 0, stream>>>(W3, W4, W5, fW1, Wf);
    hipMemsetAsync(cnt, 0, NN * sizeof(int), stream);
    k_count<<<gE, 256, 0, stream>>>(ei, cnt, slot);
    k_bsum<<<nb, 256, 0, stream>>>(cnt, bsum);
    k_scan_out<<<nb, 256, 0, stream>>>(cnt, bsum, rowptr);
    k_fill<<<gE, 256, 0, stream>>>(ei, ew, slot, rowptr, epair);
    k_deg<<<gW4, 256, 0, stream>>>(rowptr, epair, x, dinv, xd);

    // Layer 1 (scalar gather + matvec) -> G2' bf16
    k_l1<<<gW4, 256, 0, stream>>>(xd, dinv, rowptr, epair, W1, b1, W2,
                                  (unsigned short*)Ga16);
    // Layers 2..4: fused gather + MFMA matvec
    k_gmv<<<gW4, 256, 0, stream>>>(Ga16, dinv, rowptr, epair, b2, Wf + 0,
                                   (unsigned short*)Gb16);
    k_gmv<<<gW4, 256, 0, stream>>>(Gb16, dinv, rowptr, epair, b3, Wf + 4096,
                                   (unsigned short*)Ga16);
    k_gmv<<<gW4, 256, 0, stream>>>(Ga16, dinv, rowptr, epair, b4, Wf + 8192,
                                   (unsigned short*)Gb16);
    // Layer 5 + head fused
    k_ghead<<<gW4, 256, 0, stream>>>(Gb16, dinv, rowptr, epair, b5, Wf + 12288,
                                     fb1, fW2, fb2, out);
}

// Round 5
// 427.981 us; speedup vs baseline: 1.0174x; 1.0174x over previous
//
#include <hip/hip_runtime.h>
#include <hip/hip_bf16.h>

#define NN 100000
#define EE 1250000

#define RL(x, l) __builtin_amdgcn_readlane((x), (l))
#define RLF(x, l) __int_as_float(__builtin_amdgcn_readlane(__float_as_int(x), (l)))

typedef __attribute__((ext_vector_type(8))) short v8s;
typedef __attribute__((ext_vector_type(4))) float v4f;
typedef __attribute__((ext_vector_type(4))) unsigned int v4u;

__device__ __forceinline__ unsigned short bf16rtn(float x) {
    unsigned u = __float_as_uint(x);
    unsigned r = u + 0x7fffu + ((u >> 16) & 1u);
    return (unsigned short)(r >> 16);
}
__device__ __forceinline__ unsigned bf16rtn2(float lo, float hi) {
    return (unsigned)bf16rtn(lo) | ((unsigned)bf16rtn(hi) << 16);
}
__device__ __forceinline__ float bflo(unsigned u) { return __uint_as_float(u << 16); }
__device__ __forceinline__ float bfhi(unsigned u) { return __uint_as_float(u & 0xffff0000u); }
__device__ __forceinline__ float bfs(unsigned short s) { return __uint_as_float((unsigned)s << 16); }

// ---------------- CSR build (packed; R9-proven) ----------------
// Atomic pass: ~23 G returning TRANSACTIONS/s fabric ceiling (R2/R5/R9/R10;
// R14 gather counters confirm same ~20G lines/s on L2-miss traffic).
// R15: k_deg folded into the atomic — 64-bit packed add: hi dword = count
// (slot = old>>32, unchanged), lo dword = sum(ew) in 2^-24 fixed point
// (max deg ~40 << 256 -> no carry into count). Removes a full 1.25M-edge
// epair pass; dinv/xd fall out of k_scan_out.

__global__ __launch_bounds__(256) void k_count(const int* __restrict__ ei,
                                               const float* __restrict__ ew,
                                               unsigned long long* __restrict__ cnt,
                                               int* __restrict__ slot) {
    int e = blockIdx.x * 256 + threadIdx.x;
    if (e >= EE) return;
    int d = __builtin_nontemporal_load(&ei[EE + e]);
    float w = __builtin_nontemporal_load(&ew[e]);
    unsigned fx = (unsigned)(w * 16777216.0f + 0.5f);   // w in [0,1] -> <= 2^24
    unsigned long long old =
        atomicAdd(&cnt[d], (1ULL << 32) | (unsigned long long)fx);
    __builtin_nontemporal_store((int)(old >> 32), &slot[e]);
}

__global__ __launch_bounds__(256) void k_bsum(const unsigned long long* __restrict__ cnt,
                                              int* __restrict__ bsum) {
    __shared__ int ls[256];
    int b = blockIdx.x, tid = threadIdx.x;
    int base = b * 1024 + tid * 4;
    int s = 0;
    #pragma unroll
    for (int j = 0; j < 4; ++j) { int g = base + j; if (g < NN) s += (int)(cnt[g] >> 32); }
    ls[tid] = s; __syncthreads();
    for (int off = 128; off > 0; off >>= 1) {
        if (tid < off) ls[tid] += ls[tid + off];
        __syncthreads();
    }
    if (tid == 0) bsum[b] = ls[0];
}

// per-1024 scan; block base computed in-kernel from bsum.
// R15: also emits dinv[n] = rsqrt(1 + sum ew) and xd[n] = dinv[n]*x[n]
// from the fixed-point low dword (replaces k_deg).
__global__ __launch_bounds__(256) void k_scan_out(const unsigned long long* __restrict__ cnt,
                                                  const int* __restrict__ bsum,
                                                  const float* __restrict__ x,
                                                  int* __restrict__ rowptr,
                                                  float* __restrict__ dinv,
                                                  float* __restrict__ xd) {
    __shared__ int ls[256];
    __shared__ int sbase;
    int b = blockIdx.x, tid = threadIdx.x;
    if (tid < 64) {
        int w0 = (tid < b) ? bsum[tid] : 0;
        int w1 = ((64 + tid) < b) ? bsum[64 + tid] : 0;
        int s = w0 + w1;
        #pragma unroll
        for (int m = 32; m >= 1; m >>= 1) s += __shfl_xor(s, m, 64);
        if (tid == 0) sbase = s;
    }
    int base = b * 1024 + tid * 4;
    int c[4]; float sw[4]; int s = 0;
    #pragma unroll
    for (int j = 0; j < 4; ++j) {
        int g = base + j;
        unsigned long long v = (g < NN) ? cnt[g] : 0ULL;
        c[j] = (int)(v >> 32);
        sw[j] = (float)(unsigned)(v & 0xffffffffu) * (1.0f / 16777216.0f);
        s += c[j];
    }
    ls[tid] = s; __syncthreads();
    for (int off = 1; off < 256; off <<= 1) {
        int v = (tid >= off) ? ls[tid - off] : 0;
        __syncthreads();
        ls[tid] += v;
        __syncthreads();
    }
    int excl = ls[tid] - s + sbase;
    #pragma unroll
    for (int j = 0; j < 4; ++j) {
        int g = base + j;
        if (g < NN) {
            rowptr[g + 1] = excl + c[j];
            excl += c[j];
            float di = rsqrtf(sw[j] + 1.0f);
            dinv[g] = di;
            xd[g] = di * x[g];
        }
    }
    if (b == 0 && tid == 0) rowptr[0] = 0;
}

__global__ __launch_bounds__(256) void k_fill(const int* __restrict__ ei,
                                              const float* __restrict__ ew,
                                              const int* __restrict__ slot,
                                              const int* __restrict__ rowptr,
                                              int2* __restrict__ epair) {
    int e = blockIdx.x * 256 + threadIdx.x;
    if (e >= EE) return;
    int s = __builtin_nontemporal_load(&ei[e]);
    int d = __builtin_nontemporal_load(&ei[EE + e]);
    float w = __builtin_nontemporal_load(&ew[e]);
    int sl = __builtin_nontemporal_load(&slot[e]);
    int p = rowptr[d] + sl;
    epair[p] = make_int2(s, __float_as_int(w));
}

// ---------------- W pre-pack for MFMA (R12, R13-fixed) ----------------
// Packs a 64x64 row-major fp32 W into mfma_f32_16x16x32_bf16 B-fragment
// order, SPLIT hi+lo bf16 (Whi + Wlo reconstructs W to ~2^-17 rel => fp32-
// equivalent W precision; only the activation v carries bf16 rounding).
// Fragment (h, kt, nt): lane l holds 8 bf16 = W[kt*32 + (l>>4)*8 + j]
// [nt*16 + (l&15)], j=0..7, packed k-pairs per dword.  Group index
// g = (h*2+kt)*4+nt; dword addr = (g*64 + l)*4 + d.  16 KB per W.
// R13 BUGFIX: slot loop is 512 entries (i<2), NOT 1024.
// grid = 4 blocks: {W3, W4, W5, fW1}.
__global__ __launch_bounds__(256) void k_wpk(const float* __restrict__ Wa,
                                             const float* __restrict__ Wb,
                                             const float* __restrict__ Wc,
                                             const float* __restrict__ Wd,
                                             unsigned* __restrict__ Wf) {
    const float* W = (blockIdx.x == 0) ? Wa : (blockIdx.x == 1) ? Wb
                   : (blockIdx.x == 2) ? Wc : Wd;
    unsigned* out = Wf + blockIdx.x * 4096;
    int t = threadIdx.x;
    #pragma unroll
    for (int i = 0; i < 2; ++i) {
        int s = t * 2 + i;               // slot 0..511 = (kt*4+nt)*64 + lane
        int lane = s & 63;
        int nt = (s >> 6) & 3;
        int kt = s >> 8;                 // 0..1
        int col = nt * 16 + (lane & 15);
        int k0 = kt * 32 + (lane >> 4) * 8;
        unsigned hi[4], lo[4];
        #pragma unroll
        for (int d = 0; d < 4; ++d) {
            float w0 = W[(k0 + 2 * d) * 64 + col];
            float w1 = W[(k0 + 2 * d + 1) * 64 + col];
            unsigned short h0 = bf16rtn(w0), h1 = bf16rtn(w1);
            float r0 = w0 - bfs(h0), r1 = w1 - bfs(h1);
            hi[d] = (unsigned)h0 | ((unsigned)h1 << 16);
            lo[d] = (unsigned)bf16rtn(r0) | ((unsigned)bf16rtn(r1) << 16);
        }
        int gh = (0 * 2 + kt) * 4 + nt;  // 0..7
        int gl = (1 * 2 + kt) * 4 + nt;  // 8..15
        *(v4u*)&out[(gh * 64 + lane) * 4] = (v4u){hi[0], hi[1], hi[2], hi[3]};
        *(v4u*)&out[(gl * 64 + lane) * 4] = (v4u){lo[0], lo[1], lo[2], lo[3]};
    }
}

// ---------------- Layers ----------------
// Identity: Agg_l[d] = dinv_d * ( G'_l[d] + sum_e w_e * G'_l[src] ), G' = dinv (.) G.
// G' stored bf16 (rows = 32 uints = 128 B). All accumulation fp32.
// R12/R13: matvec on the MFMA pipe (sequential 4-node gather — R14's pair
// interleave was a null/regression: gathers sit at the ~20G fabric
// transactions/s ceiling, not a per-wave-MLP limit).

// Layer 1: z scalar agg + matvec, W2 via LDS. grid NN/16.
__global__ __launch_bounds__(256) void k_l1(
    const float* __restrict__ xd, const float* __restrict__ dinv,
    const int* __restrict__ rowptr, const int2* __restrict__ ep,
    const float* __restrict__ W1, const float* __restrict__ b1,
    const float* __restrict__ W2, unsigned short* __restrict__ Gout)
{
    __shared__ float sW[4096];
    int tid = threadIdx.x;
    #pragma unroll
    for (int i = 0; i < 16; ++i) sW[tid + i * 256] = W2[tid + i * 256];
    __syncthreads();
    int lane = tid & 63, l16 = lane & 15, sub = lane >> 4;
    int g4 = blockIdx.x * 4 + (tid >> 6);
    int nodeS = g4 * 4 + sub;
    int beg = rowptr[nodeS], end = rowptr[nodeS + 1];
    float partial = 0.f;
    for (int idx = beg + l16; idx < end; idx += 16) {
        int2 p = ep[idx];
        partial = fmaf(__int_as_float(p.y), xd[p.x], partial);
    }
    #pragma unroll
    for (int m = 8; m >= 1; m >>= 1) partial += __shfl_xor(partial, m, 64);
    float z = dinv[nodeS] * (xd[nodeS] + partial);   // valid where l16==0
    float z0 = RLF(z, 0), z1 = RLF(z, 16), z2 = RLF(z, 32), z3 = RLF(z, 48);
    float w1l = W1[lane], b1l = b1[lane];
    float v0 = fmaxf(fmaf(z0, w1l, b1l), 0.f);
    float v1 = fmaxf(fmaf(z1, w1l, b1l), 0.f);
    float v2 = fmaxf(fmaf(z2, w1l, b1l), 0.f);
    float v3 = fmaxf(fmaf(z3, w1l, b1l), 0.f);
    float a0 = 0.f, a1 = 0.f, a2 = 0.f, a3 = 0.f;
    #pragma unroll
    for (int k = 0; k < 64; ++k) {
        float wk = sW[k * 64 + lane];
        a0 = fmaf(RLF(v0, k), wk, a0);
        a1 = fmaf(RLF(v1, k), wk, a1);
        a2 = fmaf(RLF(v2, k), wk, a2);
        a3 = fmaf(RLF(v3, k), wk, a3);
    }
    int n0 = g4 * 4;
    Gout[(n0 + 0) * 64 + lane] = bf16rtn(dinv[n0 + 0] * a0);
    Gout[(n0 + 1) * 64 + lane] = bf16rtn(dinv[n0 + 1] * a1);
    Gout[(n0 + 2) * 64 + lane] = bf16rtn(dinv[n0 + 2] * a2);
    Gout[(n0 + 3) * 64 + lane] = bf16rtn(dinv[n0 + 3] * a3);
}

// Fused gather + bias/relu + MFMA matvec + dinv scale (layers 2..4).
// 4 nodes/wave sequential gather; grid = NN/16.
__global__ __launch_bounds__(256) void k_gmv(
    const unsigned* __restrict__ G16, const float* __restrict__ dinv,
    const int* __restrict__ rowptr, const int2* __restrict__ ep,
    const float* __restrict__ bias, const unsigned* __restrict__ Wf,
    unsigned short* __restrict__ Gout)
{
    __shared__ __align__(16) unsigned sB[4096];   // 16 KB: Whi/Wlo fragments
    __shared__ __align__(16) unsigned sA[4][128]; // per-wave A scratch (4n x 32dw)
    int tid = threadIdx.x;
    #pragma unroll
    for (int i = 0; i < 4; ++i)
        ((v4u*)sB)[tid + i * 256] = ((const v4u*)Wf)[tid + i * 256];
    int lane = tid & 63;
    int wid  = tid >> 6;
    int lc   = lane & 31;
    int half = lane >> 5;
    int n0 = (blockIdx.x * 4 + wid) * 4;
    float2 bb = ((const float2*)bias)[lc];        // (b[2lc], b[2lc+1])
    // ---- gather 4 nodes, pack v rows into sA ----
    for (int r = 0; r < 4; ++r) {
        int node = n0 + r;
        int beg = __builtin_amdgcn_readfirstlane(rowptr[node]);
        int end = __builtin_amdgcn_readfirstlane(rowptr[node + 1]);
        float ax = 0.f, ay = 0.f;
        if (half == 0) {
            unsigned u = G16[node * 32 + lc];
            ax = bflo(u); ay = bfhi(u);
        }
        int j = beg;
        for (; j + 16 <= end; j += 16) {          // full batch: 16 edges, 8 loads
            unsigned u[8]; float nv[8];
            #pragma unroll
            for (int t = 0; t < 8; ++t) {
                int2 pa = ep[j + t];              // uniform -> s_load
                int2 pb = ep[j + 8 + t];          // uniform -> s_load
                int src = half ? pb.x : pa.x;
                nv[t] = __int_as_float(half ? pb.y : pa.y);
                u[t] = G16[src * 32 + lc];
            }
            #pragma unroll
            for (int t = 0; t < 8; ++t) {
                ax = fmaf(bflo(u[t]), nv[t], ax);
                ay = fmaf(bfhi(u[t]), nv[t], ay);
            }
        }
        if (j < end) {                            // masked batch (tail 1..15)
            unsigned u[8]; float nv[8];
            #pragma unroll
            for (int t = 0; t < 8; ++t) {
                int ia = j + t, ib = j + 8 + t;   // uniform
                int2 pa = ep[ia < end ? ia : j];
                int2 pb = ep[ib < end ? ib : j];
                int src = half ? pb.x : pa.x;
                float w = __int_as_float(half ? pb.y : pa.y);
                bool v = half ? (ib < end) : (ia < end);
                nv[t] = v ? w : 0.f;
                u[t] = G16[src * 32 + lc];
            }
            #pragma unroll
            for (int t = 0; t < 8; ++t) {
                ax = fmaf(bflo(u[t]), nv[t], ax);
                ay = fmaf(bfhi(u[t]), nv[t], ay);
            }
        }
        ax += __shfl_xor(ax, 32, 64);             // both halves hold full sums
        ay += __shfl_xor(ay, 32, 64);
        float din = dinv[node];
        float ve = fmaxf(fmaf(din, ax, bb.x), 0.f);
        float vo = fmaxf(fmaf(din, ay, bb.y), 0.f);
        if (half == 0) sA[wid][r * 32 + lc] = bf16rtn2(ve, vo); // k-pair (2lc,2lc+1)
    }
    __syncthreads();                              // sB ready (sA is wave-local)
    // ---- matvec on MFMA pipe ----
    int rr  = lane & 3;                           // A row (rows 4-15 = dup, unused)
    int blk = lane >> 4;
    v8s a0 = *(const v8s*)&sA[wid][rr * 32 +  0 + blk * 4];   // kt=0
    v8s a1 = *(const v8s*)&sA[wid][rr * 32 + 16 + blk * 4];   // kt=1
    v4f acc[4];
    #pragma unroll
    for (int nt = 0; nt < 4; ++nt) {
        v8s bh0 = *(const v8s*)&sB[((0 * 4 + nt) * 64 + lane) * 4];  // h=0 kt=0
        v8s bh1 = *(const v8s*)&sB[((1 * 4 + nt) * 64 + lane) * 4];  // h=0 kt=1
        v8s bl0 = *(const v8s*)&sB[((2 * 4 + nt) * 64 + lane) * 4];  // h=1 kt=0
        v8s bl1 = *(const v8s*)&sB[((3 * 4 + nt) * 64 + lane) * 4];  // h=1 kt=1
        v4f c = {0.f, 0.f, 0.f, 0.f};
        c = __builtin_amdgcn_mfma_f32_16x16x32_bf16(a0, bl0, c, 0, 0, 0);
        c = __builtin_amdgcn_mfma_f32_16x16x32_bf16(a1, bl1, c, 0, 0, 0);
        c = __builtin_amdgcn_mfma_f32_16x16x32_bf16(a0, bh0, c, 0, 0, 0);
        c = __builtin_amdgcn_mfma_f32_16x16x32_bf16(a1, bh1, c, 0, 0, 0);
        acc[nt] = c;
    }
    // lanes 0-15: acc[nt][r] = node n0+r, feature nt*16+lane
    if (lane < 16) {
        float4 dn = *(const float4*)&dinv[n0];
        #pragma unroll
        for (int r = 0; r < 4; ++r) {
            float d = (r == 0) ? dn.x : (r == 1) ? dn.y : (r == 2) ? dn.z : dn.w;
            #pragma unroll
            for (int nt = 0; nt < 4; ++nt)
                Gout[(n0 + r) * 64 + nt * 16 + lane] = bf16rtn(d * acc[nt][r]);
        }
    }
}

// Fused gather + layer-5 bias/relu + head (fW1 MFMA matvec, relu, fW2 dot).
// Same 4-node/wave structure; grid = NN/16.
__global__ __launch_bounds__(256) void k_ghead(
    const unsigned* __restrict__ G16, const float* __restrict__ dinv,
    const int* __restrict__ rowptr, const int2* __restrict__ ep,
    const float* __restrict__ b5, const unsigned* __restrict__ Wf,
    const float* __restrict__ fb1, const float* __restrict__ fW2,
    const float* __restrict__ fb2, float* __restrict__ out)
{
    __shared__ __align__(16) unsigned sB[4096];
    __shared__ __align__(16) unsigned sA[4][128];
    int tid = threadIdx.x;
    #pragma unroll
    for (int i = 0; i < 4; ++i)
        ((v4u*)sB)[tid + i * 256] = ((const v4u*)Wf)[tid + i * 256];
    int lane = tid & 63;
    int wid  = tid >> 6;
    int lc   = lane & 31;
    int half = lane >> 5;
    int n0 = (blockIdx.x * 4 + wid) * 4;
    float2 bb = ((const float2*)b5)[lc];
    int l16 = lane & 15;
    float fb1v[4], fw2v[4];
    #pragma unroll
    for (int nt = 0; nt < 4; ++nt) {
        fb1v[nt] = fb1[nt * 16 + l16];
        fw2v[nt] = fW2[nt * 16 + l16];
    }
    float fb2s = fb2[0];
    for (int r = 0; r < 4; ++r) {
        int node = n0 + r;
        int beg = __builtin_amdgcn_readfirstlane(rowptr[node]);
        int end = __builtin_amdgcn_readfirstlane(rowptr[node + 1]);
        float ax = 0.f, ay = 0.f;
        if (half == 0) {
            unsigned u = G16[node * 32 + lc];
            ax = bflo(u); ay = bfhi(u);
        }
        int j = beg;
        for (; j + 16 <= end; j += 16) {
            unsigned u[8]; float nv[8];
            #pragma unroll
            for (int t = 0; t < 8; ++t) {
                int2 pa = ep[j + t];
                int2 pb = ep[j + 8 + t];
                int src = half ? pb.x : pa.x;
                nv[t] = __int_as_float(half ? pb.y : pa.y);
                u[t] = G16[src * 32 + lc];
            }
            #pragma unroll
            for (int t = 0; t < 8; ++t) {
                ax = fmaf(bflo(u[t]), nv[t], ax);
                ay = fmaf(bfhi(u[t]), nv[t], ay);
            }
        }
        if (j < end) {
            unsigned u[8]; float nv[8];
            #pragma unroll
            for (int t = 0; t < 8; ++t) {
                int ia = j + t, ib = j + 8 + t;
                int2 pa = ep[ia < end ? ia : j];
                int2 pb = ep[ib < end ? ib : j];
                int src = half ? pb.x : pa.x;
                float w = __int_as_float(half ? pb.y : pa.y);
                bool v = half ? (ib < end) : (ia < end);
                nv[t] = v ? w : 0.f;
                u[t] = G16[src * 32 + lc];
            }
            #pragma unroll
            for (int t = 0; t < 8; ++t) {
                ax = fmaf(bflo(u[t]), nv[t], ax);
                ay = fmaf(bfhi(u[t]), nv[t], ay);
            }
        }
        ax += __shfl_xor(ax, 32, 64);
        ay += __shfl_xor(ay, 32, 64);
        float din = dinv[node];
        float ve = fmaxf(fmaf(din, ax, bb.x), 0.f);
        float vo = fmaxf(fmaf(din, ay, bb.y), 0.f);
        if (half == 0) sA[wid][r * 32 + lc] = bf16rtn2(ve, vo);
    }
    __syncthreads();
    int rr  = lane & 3;
    int blk = lane >> 4;
    v8s a0 = *(const v8s*)&sA[wid][rr * 32 +  0 + blk * 4];
    v8s a1 = *(const v8s*)&sA[wid][rr * 32 + 16 + blk * 4];
    v4f acc[4];
    #pragma unroll
    for (int nt = 0; nt < 4; ++nt) {
        v8s bh0 = *(const v8s*)&sB[((0 * 4 + nt) * 64 + lane) * 4];
        v8s bh1 = *(const v8s*)&sB[((1 * 4 + nt) * 64 + lane) * 4];
        v8s bl0 = *(const v8s*)&sB[((2 * 4 + nt) * 64 + lane) * 4];
        v8s bl1 = *(const v8s*)&sB[((3 * 4 + nt) * 64 + lane) * 4];
        v4f c = {0.f, 0.f, 0.f, 0.f};
        c = __builtin_amdgcn_mfma_f32_16x16x32_bf16(a0, bl0, c, 0, 0, 0);
        c = __builtin_amdgcn_mfma_f32_16x16x32_bf16(a1, bl1, c, 0, 0, 0);
        c = __builtin_amdgcn_mfma_f32_16x16x32_bf16(a0, bh0, c, 0, 0, 0);
        c = __builtin_amdgcn_mfma_f32_16x16x32_bf16(a1, bh1, c, 0, 0, 0);
        acc[nt] = c;
    }
    // all lanes hold a dup copy: lane l, reg r -> node n0+r, col l&15
    float tr[4];
    #pragma unroll
    for (int r = 0; r < 4; ++r) {
        float t = 0.f;
        #pragma unroll
        for (int nt = 0; nt < 4; ++nt)
            t += fmaxf(acc[nt][r] + fb1v[nt], 0.f) * fw2v[nt];
        #pragma unroll
        for (int m = 8; m >= 1; m >>= 1) t += __shfl_xor(t, m, 64);
        tr[r] = t;
    }
    if (lane == 0) {
        float4 o = {tr[0] + fb2s, tr[1] + fb2s, tr[2] + fb2s, tr[3] + fb2s};
        *(float4*)&out[n0] = o;
    }
}

// ---------------- Launch ----------------

extern "C" void kernel_launch(void* const* d_in, const int* in_sizes, int n_in,
                              void* d_out, int out_size, void* d_ws, size_t ws_size,
                              hipStream_t stream) {
    const float* x   = (const float*)d_in[0];
    const int*   ei  = (const int*)d_in[1];
    const float* ew  = (const float*)d_in[2];
    const float* W1  = (const float*)d_in[3];
    const float* b1  = (const float*)d_in[4];
    const float* W2  = (const float*)d_in[5];
    const float* b2  = (const float*)d_in[6];
    const float* W3  = (const float*)d_in[7];
    const float* b3  = (const float*)d_in[8];
    const float* W4  = (const float*)d_in[9];
    const float* b4  = (const float*)d_in[10];
    const float* W5  = (const float*)d_in[11];
    const float* b5  = (const float*)d_in[12];
    const float* fW1 = (const float*)d_in[13];
    const float* fb1 = (const float*)d_in[14];
    const float* fW2 = (const float*)d_in[15];
    const float* fb2 = (const float*)d_in[16];
    float* out = (float*)d_out;

    char* ws = (char*)d_ws;
    size_t o = 0;
    auto alloc = [&](size_t elems) -> void* {
        void* p = (void*)(ws + o);
        o += ((elems * 4 + 255) / 256) * 256;
        return p;
    };
    float* dinv   = (float*)alloc(NN);
    float* xd     = (float*)alloc(NN);
    int*   rowptr = (int*)alloc(NN + 1);
    unsigned long long* cnt64 = (unsigned long long*)alloc(2 * (size_t)NN);
    int*   bsum   = (int*)alloc(128);
    int2*  epair  = (int2*)alloc(2 * (size_t)EE);
    unsigned* Ga16 = (unsigned*)alloc((size_t)NN * 32);   // bf16 feature rows
    unsigned* Gb16 = (unsigned*)alloc((size_t)NN * 32);
    int*   slot   = (int*)alloc(EE);
    unsigned* Wf  = (unsigned*)alloc(4 * 4096);           // pre-packed W frags

    int gE  = (EE + 255) / 256;
    int nb  = (NN + 1023) / 1024;    // 98
    int gW4 = NN / 16;               // 6250: 4 waves x 4 nodes per block

    k_wpk<<<4, 256, 0, stream>>>(W3, W4, W5, fW1, Wf);
    hipMemsetAsync(cnt64, 0, NN * sizeof(unsigned long long), stream);
    k_count<<<gE, 256, 0, stream>>>(ei, ew, cnt64, slot);
    k_bsum<<<nb, 256, 0, stream>>>(cnt64, bsum);
    k_scan_out<<<nb, 256, 0, stream>>>(cnt64, bsum, x, rowptr, dinv, xd);
    k_fill<<<gE, 256, 0, stream>>>(ei, ew, slot, rowptr, epair);

    // Layer 1 (scalar gather + matvec) -> G2' bf16
    k_l1<<<gW4, 256, 0, stream>>>(xd, dinv, rowptr, epair, W1, b1, W2,
                                  (unsigned short*)Ga16);
    // Layers 2..4: fused gather + MFMA matvec
    k_gmv<<<gW4, 256, 0, stream>>>(Ga16, dinv, rowptr, epair, b2, Wf + 0,
                                   (unsigned short*)Gb16);
    k_gmv<<<gW4, 256, 0, stream>>>(Gb16, dinv, rowptr, epair, b3, Wf + 4096,
                                   (unsigned short*)Ga16);
    k_gmv<<<gW4, 256, 0, stream>>>(Ga16, dinv, rowptr, epair, b4, Wf + 8192,
                                   (unsigned short*)Gb16);
    // Layer 5 + head fused
    k_ghead<<<gW4, 256, 0, stream>>>(Gb16, dinv, rowptr, epair, b5, Wf + 12288,
                                     fb1, fW2, fb2, out);
}

// Round 6
// 399.672 us; speedup vs baseline: 1.0895x; 1.0708x over previous
//
#include <hip/hip_runtime.h>
#include <hip/hip_bf16.h>

#define NN 100000
#define EE 1250000

#define RL(x, l) __builtin_amdgcn_readlane((x), (l))
#define RLF(x, l) __int_as_float(__builtin_amdgcn_readlane(__float_as_int(x), (l)))

typedef __attribute__((ext_vector_type(8))) short v8s;
typedef __attribute__((ext_vector_type(4))) float v4f;
typedef __attribute__((ext_vector_type(4))) unsigned int v4u;

__device__ __forceinline__ unsigned short bf16rtn(float x) {
    unsigned u = __float_as_uint(x);
    unsigned r = u + 0x7fffu + ((u >> 16) & 1u);
    return (unsigned short)(r >> 16);
}
__device__ __forceinline__ unsigned bf16rtn2(float lo, float hi) {
    return (unsigned)bf16rtn(lo) | ((unsigned)bf16rtn(hi) << 16);
}
__device__ __forceinline__ float bflo(unsigned u) { return __uint_as_float(u << 16); }
__device__ __forceinline__ float bfhi(unsigned u) { return __uint_as_float(u & 0xffff0000u); }
__device__ __forceinline__ float bfs(unsigned short s) { return __uint_as_float((unsigned)s << 16); }

// ---------------- CSR build (packed; R9-proven) ----------------
// Atomic pass: ~23 G returning TRANSACTIONS/s fabric ceiling (R2/R5/R9/R10).
// R15: k_deg folded into the atomic — 64-bit packed add: hi dword = count
// (slot = old>>32), lo dword = sum(ew) in 2^-24 fixed point. 64-bit atomic
// costs ~11%/transaction vs 32-bit but removes the k_deg pass (net wash,
// one fewer kernel).

__global__ __launch_bounds__(256) void k_count(const int* __restrict__ ei,
                                               const float* __restrict__ ew,
                                               unsigned long long* __restrict__ cnt,
                                               int* __restrict__ slot) {
    int e = blockIdx.x * 256 + threadIdx.x;
    if (e >= EE) return;
    int d = __builtin_nontemporal_load(&ei[EE + e]);
    float w = __builtin_nontemporal_load(&ew[e]);
    unsigned fx = (unsigned)(w * 16777216.0f + 0.5f);   // w in [0,1] -> <= 2^24
    unsigned long long old =
        atomicAdd(&cnt[d], (1ULL << 32) | (unsigned long long)fx);
    __builtin_nontemporal_store((int)(old >> 32), &slot[e]);
}

__global__ __launch_bounds__(256) void k_bsum(const unsigned long long* __restrict__ cnt,
                                              int* __restrict__ bsum) {
    __shared__ int ls[256];
    int b = blockIdx.x, tid = threadIdx.x;
    int base = b * 1024 + tid * 4;
    int s = 0;
    #pragma unroll
    for (int j = 0; j < 4; ++j) { int g = base + j; if (g < NN) s += (int)(cnt[g] >> 32); }
    ls[tid] = s; __syncthreads();
    for (int off = 128; off > 0; off >>= 1) {
        if (tid < off) ls[tid] += ls[tid + off];
        __syncthreads();
    }
    if (tid == 0) bsum[b] = ls[0];
}

// per-1024 scan; block base computed in-kernel from bsum.
// R15: also emits dinv[n] = rsqrt(1 + sum ew) and xd[n] = dinv[n]*x[n].
__global__ __launch_bounds__(256) void k_scan_out(const unsigned long long* __restrict__ cnt,
                                                  const int* __restrict__ bsum,
                                                  const float* __restrict__ x,
                                                  int* __restrict__ rowptr,
                                                  float* __restrict__ dinv,
                                                  float* __restrict__ xd) {
    __shared__ int ls[256];
    __shared__ int sbase;
    int b = blockIdx.x, tid = threadIdx.x;
    if (tid < 64) {
        int w0 = (tid < b) ? bsum[tid] : 0;
        int w1 = ((64 + tid) < b) ? bsum[64 + tid] : 0;
        int s = w0 + w1;
        #pragma unroll
        for (int m = 32; m >= 1; m >>= 1) s += __shfl_xor(s, m, 64);
        if (tid == 0) sbase = s;
    }
    int base = b * 1024 + tid * 4;
    int c[4]; float sw[4]; int s = 0;
    #pragma unroll
    for (int j = 0; j < 4; ++j) {
        int g = base + j;
        unsigned long long v = (g < NN) ? cnt[g] : 0ULL;
        c[j] = (int)(v >> 32);
        sw[j] = (float)(unsigned)(v & 0xffffffffu) * (1.0f / 16777216.0f);
        s += c[j];
    }
    ls[tid] = s; __syncthreads();
    for (int off = 1; off < 256; off <<= 1) {
        int v = (tid >= off) ? ls[tid - off] : 0;
        __syncthreads();
        ls[tid] += v;
        __syncthreads();
    }
    int excl = ls[tid] - s + sbase;
    #pragma unroll
    for (int j = 0; j < 4; ++j) {
        int g = base + j;
        if (g < NN) {
            rowptr[g + 1] = excl + c[j];
            excl += c[j];
            float di = rsqrtf(sw[j] + 1.0f);
            dinv[g] = di;
            xd[g] = di * x[g];
        }
    }
    if (b == 0 && tid == 0) rowptr[0] = 0;
}

__global__ __launch_bounds__(256) void k_fill(const int* __restrict__ ei,
                                              const float* __restrict__ ew,
                                              const int* __restrict__ slot,
                                              const int* __restrict__ rowptr,
                                              int2* __restrict__ epair) {
    int e = blockIdx.x * 256 + threadIdx.x;
    if (e >= EE) return;
    int s = __builtin_nontemporal_load(&ei[e]);
    int d = __builtin_nontemporal_load(&ei[EE + e]);
    float w = __builtin_nontemporal_load(&ew[e]);
    int sl = __builtin_nontemporal_load(&slot[e]);
    int p = rowptr[d] + sl;
    epair[p] = make_int2(s, __float_as_int(w));
}

// ---------------- W pre-pack for MFMA (R12, R13-fixed) ----------------
// Packs a 64x64 row-major fp32 W into mfma_f32_16x16x32_bf16 B-fragment
// order, SPLIT hi+lo bf16 (Whi + Wlo reconstructs W to ~2^-17 rel => fp32-
// equivalent W precision; only the activation v carries bf16 rounding).
// Fragment (h, kt, nt): lane l holds 8 bf16 = W[kt*32 + (l>>4)*8 + j]
// [nt*16 + (l&15)], j=0..7, packed k-pairs per dword.  Group index
// g = (h*2+kt)*4+nt; dword addr = (g*64 + l)*4 + d.  16 KB per W.
// R13 BUGFIX: slot loop is 512 entries (i<2), NOT 1024.
// grid = 4 blocks: {W3, W4, W5, fW1}.
__global__ __launch_bounds__(256) void k_wpk(const float* __restrict__ Wa,
                                             const float* __restrict__ Wb,
                                             const float* __restrict__ Wc,
                                             const float* __restrict__ Wd,
                                             unsigned* __restrict__ Wf) {
    const float* W = (blockIdx.x == 0) ? Wa : (blockIdx.x == 1) ? Wb
                   : (blockIdx.x == 2) ? Wc : Wd;
    unsigned* out = Wf + blockIdx.x * 4096;
    int t = threadIdx.x;
    #pragma unroll
    for (int i = 0; i < 2; ++i) {
        int s = t * 2 + i;               // slot 0..511 = (kt*4+nt)*64 + lane
        int lane = s & 63;
        int nt = (s >> 6) & 3;
        int kt = s >> 8;                 // 0..1
        int col = nt * 16 + (lane & 15);
        int k0 = kt * 32 + (lane >> 4) * 8;
        unsigned hi[4], lo[4];
        #pragma unroll
        for (int d = 0; d < 4; ++d) {
            float w0 = W[(k0 + 2 * d) * 64 + col];
            float w1 = W[(k0 + 2 * d + 1) * 64 + col];
            unsigned short h0 = bf16rtn(w0), h1 = bf16rtn(w1);
            float r0 = w0 - bfs(h0), r1 = w1 - bfs(h1);
            hi[d] = (unsigned)h0 | ((unsigned)h1 << 16);
            lo[d] = (unsigned)bf16rtn(r0) | ((unsigned)bf16rtn(r1) << 16);
        }
        int gh = (0 * 2 + kt) * 4 + nt;  // 0..7
        int gl = (1 * 2 + kt) * 4 + nt;  // 8..15
        *(v4u*)&out[(gh * 64 + lane) * 4] = (v4u){hi[0], hi[1], hi[2], hi[3]};
        *(v4u*)&out[(gl * 64 + lane) * 4] = (v4u){lo[0], lo[1], lo[2], lo[3]};
    }
}

// ---------------- Quarter-wave gather (R16) ----------------
// Latency fix done STRUCTURALLY (R14's compiler-interleave was null): one
// node per 16-lane quarter; lane l16 owns features 4*l16..4*l16+3 via one
// uint2 load per edge (16 lanes x 8B = full 128B row). All 4 nodes advance
// in the same instruction stream -> each 8-deep batch holds 32 rows in
// flight per wave (vs 8), serial batch-waits per wave drop ~7 -> ~2.5.
// No cross-lane reduction needed (features lane-private); sA k-pair packing
// preserved (lane writes dwords 2*l16, 2*l16+1 of row q).
// Accumulates per-feature fp32 over self + edges in CSR order.
__device__ __forceinline__ void gatherq(
    const unsigned* __restrict__ G16, const int2* __restrict__ ep,
    int node, int beg, int end, int l16,
    float& a0, float& a1, float& a2, float& a3)
{
    uint2 su = *(const uint2*)&G16[node * 32 + l16 * 2];
    a0 = bflo(su.x); a1 = bfhi(su.x);
    a2 = bflo(su.y); a3 = bfhi(su.y);
    int j = beg;
    for (; j + 8 <= end; j += 8) {            // full batch: 8 edges
        uint2 u[8]; float nv[8];
        #pragma unroll
        for (int t = 0; t < 8; ++t) {
            int2 p = ep[j + t];               // 16 lanes same addr -> merged
            nv[t] = __int_as_float(p.y);
            u[t] = *(const uint2*)&G16[p.x * 32 + l16 * 2];
        }
        #pragma unroll
        for (int t = 0; t < 8; ++t) {
            a0 = fmaf(bflo(u[t].x), nv[t], a0);
            a1 = fmaf(bfhi(u[t].x), nv[t], a1);
            a2 = fmaf(bflo(u[t].y), nv[t], a2);
            a3 = fmaf(bfhi(u[t].y), nv[t], a3);
        }
    }
    if (j < end) {                            // masked tail 1..7
        uint2 u[8]; float nv[8];
        #pragma unroll
        for (int t = 0; t < 8; ++t) {
            int idx = j + t;
            int2 p = ep[idx < end ? idx : j];
            nv[t] = (idx < end) ? __int_as_float(p.y) : 0.f;
            u[t] = *(const uint2*)&G16[p.x * 32 + l16 * 2];
        }
        #pragma unroll
        for (int t = 0; t < 8; ++t) {
            a0 = fmaf(bflo(u[t].x), nv[t], a0);
            a1 = fmaf(bfhi(u[t].x), nv[t], a1);
            a2 = fmaf(bflo(u[t].y), nv[t], a2);
            a3 = fmaf(bfhi(u[t].y), nv[t], a3);
        }
    }
}

// ---------------- Layers ----------------
// Identity: Agg_l[d] = dinv_d * ( G'_l[d] + sum_e w_e * G'_l[src] ), G' = dinv (.) G.
// G' stored bf16 (rows = 32 uints = 128 B). All accumulation fp32.
// R12/R13: matvec on the MFMA pipe. R16: quarter-wave gather.

// Layer 1: z scalar agg + matvec, W2 via LDS. grid NN/16.
__global__ __launch_bounds__(256) void k_l1(
    const float* __restrict__ xd, const float* __restrict__ dinv,
    const int* __restrict__ rowptr, const int2* __restrict__ ep,
    const float* __restrict__ W1, const float* __restrict__ b1,
    const float* __restrict__ W2, unsigned short* __restrict__ Gout)
{
    __shared__ float sW[4096];
    int tid = threadIdx.x;
    #pragma unroll
    for (int i = 0; i < 16; ++i) sW[tid + i * 256] = W2[tid + i * 256];
    __syncthreads();
    int lane = tid & 63, l16 = lane & 15, sub = lane >> 4;
    int g4 = blockIdx.x * 4 + (tid >> 6);
    int nodeS = g4 * 4 + sub;
    int beg = rowptr[nodeS], end = rowptr[nodeS + 1];
    float partial = 0.f;
    for (int idx = beg + l16; idx < end; idx += 16) {
        int2 p = ep[idx];
        partial = fmaf(__int_as_float(p.y), xd[p.x], partial);
    }
    #pragma unroll
    for (int m = 8; m >= 1; m >>= 1) partial += __shfl_xor(partial, m, 64);
    float z = dinv[nodeS] * (xd[nodeS] + partial);   // valid where l16==0
    float z0 = RLF(z, 0), z1 = RLF(z, 16), z2 = RLF(z, 32), z3 = RLF(z, 48);
    float w1l = W1[lane], b1l = b1[lane];
    float v0 = fmaxf(fmaf(z0, w1l, b1l), 0.f);
    float v1 = fmaxf(fmaf(z1, w1l, b1l), 0.f);
    float v2 = fmaxf(fmaf(z2, w1l, b1l), 0.f);
    float v3 = fmaxf(fmaf(z3, w1l, b1l), 0.f);
    float a0 = 0.f, a1 = 0.f, a2 = 0.f, a3 = 0.f;
    #pragma unroll
    for (int k = 0; k < 64; ++k) {
        float wk = sW[k * 64 + lane];
        a0 = fmaf(RLF(v0, k), wk, a0);
        a1 = fmaf(RLF(v1, k), wk, a1);
        a2 = fmaf(RLF(v2, k), wk, a2);
        a3 = fmaf(RLF(v3, k), wk, a3);
    }
    int n0 = g4 * 4;
    Gout[(n0 + 0) * 64 + lane] = bf16rtn(dinv[n0 + 0] * a0);
    Gout[(n0 + 1) * 64 + lane] = bf16rtn(dinv[n0 + 1] * a1);
    Gout[(n0 + 2) * 64 + lane] = bf16rtn(dinv[n0 + 2] * a2);
    Gout[(n0 + 3) * 64 + lane] = bf16rtn(dinv[n0 + 3] * a3);
}

// Fused quarter-gather + bias/relu + MFMA matvec + dinv scale (layers 2..4).
// grid = NN/16.
__global__ __launch_bounds__(256) void k_gmv(
    const unsigned* __restrict__ G16, const float* __restrict__ dinv,
    const int* __restrict__ rowptr, const int2* __restrict__ ep,
    const float* __restrict__ bias, const unsigned* __restrict__ Wf,
    unsigned short* __restrict__ Gout)
{
    __shared__ __align__(16) unsigned sB[4096];   // 16 KB: Whi/Wlo fragments
    __shared__ __align__(16) unsigned sA[4][128]; // per-wave A scratch (4n x 32dw)
    int tid = threadIdx.x;
    #pragma unroll
    for (int i = 0; i < 4; ++i)
        ((v4u*)sB)[tid + i * 256] = ((const v4u*)Wf)[tid + i * 256];
    int lane = tid & 63;
    int wid  = tid >> 6;
    int q    = lane >> 4;                         // quarter = node slot
    int l16  = lane & 15;
    int n0 = (blockIdx.x * 4 + wid) * 4;
    int node = n0 + q;
    int beg = rowptr[node], end = rowptr[node + 1];
    float a0, a1, a2, a3;
    gatherq(G16, ep, node, beg, end, l16, a0, a1, a2, a3);
    float din = dinv[node];
    float4 bv = *(const float4*)&bias[l16 * 4];   // features 4*l16..+3
    float v0 = fmaxf(fmaf(din, a0, bv.x), 0.f);
    float v1 = fmaxf(fmaf(din, a1, bv.y), 0.f);
    float v2 = fmaxf(fmaf(din, a2, bv.z), 0.f);
    float v3 = fmaxf(fmaf(din, a3, bv.w), 0.f);
    *(uint2*)&sA[wid][q * 32 + l16 * 2] =
        make_uint2(bf16rtn2(v0, v1), bf16rtn2(v2, v3)); // k-pairs (4l16..)
    __syncthreads();                              // sB ready (sA wave-local)
    // ---- matvec on MFMA pipe ----
    int rr  = lane & 3;                           // A row (rows 4-15 = dup, unused)
    int blk = lane >> 4;
    v8s fa0 = *(const v8s*)&sA[wid][rr * 32 +  0 + blk * 4];   // kt=0
    v8s fa1 = *(const v8s*)&sA[wid][rr * 32 + 16 + blk * 4];   // kt=1
    v4f acc[4];
    #pragma unroll
    for (int nt = 0; nt < 4; ++nt) {
        v8s bh0 = *(const v8s*)&sB[((0 * 4 + nt) * 64 + lane) * 4];  // h=0 kt=0
        v8s bh1 = *(const v8s*)&sB[((1 * 4 + nt) * 64 + lane) * 4];  // h=0 kt=1
        v8s bl0 = *(const v8s*)&sB[((2 * 4 + nt) * 64 + lane) * 4];  // h=1 kt=0
        v8s bl1 = *(const v8s*)&sB[((3 * 4 + nt) * 64 + lane) * 4];  // h=1 kt=1
        v4f c = {0.f, 0.f, 0.f, 0.f};
        c = __builtin_amdgcn_mfma_f32_16x16x32_bf16(fa0, bl0, c, 0, 0, 0);
        c = __builtin_amdgcn_mfma_f32_16x16x32_bf16(fa1, bl1, c, 0, 0, 0);
        c = __builtin_amdgcn_mfma_f32_16x16x32_bf16(fa0, bh0, c, 0, 0, 0);
        c = __builtin_amdgcn_mfma_f32_16x16x32_bf16(fa1, bh1, c, 0, 0, 0);
        acc[nt] = c;
    }
    // lanes 0-15: acc[nt][r] = node n0+r, feature nt*16+lane
    if (lane < 16) {
        float4 dn = *(const float4*)&dinv[n0];
        #pragma unroll
        for (int r = 0; r < 4; ++r) {
            float d = (r == 0) ? dn.x : (r == 1) ? dn.y : (r == 2) ? dn.z : dn.w;
            #pragma unroll
            for (int nt = 0; nt < 4; ++nt)
                Gout[(n0 + r) * 64 + nt * 16 + lane] = bf16rtn(d * acc[nt][r]);
        }
    }
}

// Fused quarter-gather + layer-5 bias/relu + head (fW1 MFMA, relu, fW2 dot).
// grid = NN/16.
__global__ __launch_bounds__(256) void k_ghead(
    const unsigned* __restrict__ G16, const float* __restrict__ dinv,
    const int* __restrict__ rowptr, const int2* __restrict__ ep,
    const float* __restrict__ b5, const unsigned* __restrict__ Wf,
    const float* __restrict__ fb1, const float* __restrict__ fW2,
    const float* __restrict__ fb2, float* __restrict__ out)
{
    __shared__ __align__(16) unsigned sB[4096];
    __shared__ __align__(16) unsigned sA[4][128];
    int tid = threadIdx.x;
    #pragma unroll
    for (int i = 0; i < 4; ++i)
        ((v4u*)sB)[tid + i * 256] = ((const v4u*)Wf)[tid + i * 256];
    int lane = tid & 63;
    int wid  = tid >> 6;
    int q    = lane >> 4;
    int l16  = lane & 15;
    int n0 = (blockIdx.x * 4 + wid) * 4;
    int node = n0 + q;
    float fb1v[4], fw2v[4];
    #pragma unroll
    for (int nt = 0; nt < 4; ++nt) {
        fb1v[nt] = fb1[nt * 16 + l16];
        fw2v[nt] = fW2[nt * 16 + l16];
    }
    float fb2s = fb2[0];
    int beg = rowptr[node], end = rowptr[node + 1];
    float a0, a1, a2, a3;
    gatherq(G16, ep, node, beg, end, l16, a0, a1, a2, a3);
    float din = dinv[node];
    float4 bv = *(const float4*)&b5[l16 * 4];
    float v0 = fmaxf(fmaf(din, a0, bv.x), 0.f);
    float v1 = fmaxf(fmaf(din, a1, bv.y), 0.f);
    float v2 = fmaxf(fmaf(din, a2, bv.z), 0.f);
    float v3 = fmaxf(fmaf(din, a3, bv.w), 0.f);
    *(uint2*)&sA[wid][q * 32 + l16 * 2] =
        make_uint2(bf16rtn2(v0, v1), bf16rtn2(v2, v3));
    __syncthreads();
    int rr  = lane & 3;
    int blk = lane >> 4;
    v8s fa0 = *(const v8s*)&sA[wid][rr * 32 +  0 + blk * 4];
    v8s fa1 = *(const v8s*)&sA[wid][rr * 32 + 16 + blk * 4];
    v4f acc[4];
    #pragma unroll
    for (int nt = 0; nt < 4; ++nt) {
        v8s bh0 = *(const v8s*)&sB[((0 * 4 + nt) * 64 + lane) * 4];
        v8s bh1 = *(const v8s*)&sB[((1 * 4 + nt) * 64 + lane) * 4];
        v8s bl0 = *(const v8s*)&sB[((2 * 4 + nt) * 64 + lane) * 4];
        v8s bl1 = *(const v8s*)&sB[((3 * 4 + nt) * 64 + lane) * 4];
        v4f c = {0.f, 0.f, 0.f, 0.f};
        c = __builtin_amdgcn_mfma_f32_16x16x32_bf16(fa0, bl0, c, 0, 0, 0);
        c = __builtin_amdgcn_mfma_f32_16x16x32_bf16(fa1, bl1, c, 0, 0, 0);
        c = __builtin_amdgcn_mfma_f32_16x16x32_bf16(fa0, bh0, c, 0, 0, 0);
        c = __builtin_amdgcn_mfma_f32_16x16x32_bf16(fa1, bh1, c, 0, 0, 0);
        acc[nt] = c;
    }
    // all lanes hold a dup copy: lane l, reg r -> node n0+r, col l&15
    float tr[4];
    #pragma unroll
    for (int r = 0; r < 4; ++r) {
        float t = 0.f;
        #pragma unroll
        for (int nt = 0; nt < 4; ++nt)
            t += fmaxf(acc[nt][r] + fb1v[nt], 0.f) * fw2v[nt];
        #pragma unroll
        for (int m = 8; m >= 1; m >>= 1) t += __shfl_xor(t, m, 64);
        tr[r] = t;
    }
    if (lane == 0) {
        float4 o = {tr[0] + fb2s, tr[1] + fb2s, tr[2] + fb2s, tr[3] + fb2s};
        *(float4*)&out[n0] = o;
    }
}

// ---------------- Launch ----------------

extern "C" void kernel_launch(void* const* d_in, const int* in_sizes, int n_in,
                              void* d_out, int out_size, void* d_ws, size_t ws_size,
                              hipStream_t stream) {
    const float* x   = (const float*)d_in[0];
    const int*   ei  = (const int*)d_in[1];
    const float* ew  = (const float*)d_in[2];
    const float* W1  = (const float*)d_in[3];
    const float* b1  = (const float*)d_in[4];
    const float* W2  = (const float*)d_in[5];
    const float* b2  = (const float*)d_in[6];
    const float* W3  = (const float*)d_in[7];
    const float* b3  = (const float*)d_in[8];
    const float* W4  = (const float*)d_in[9];
    const float* b4  = (const float*)d_in[10];
    const float* W5  = (const float*)d_in[11];
    const float* b5  = (const float*)d_in[12];
    const float* fW1 = (const float*)d_in[13];
    const float* fb1 = (const float*)d_in[14];
    const float* fW2 = (const float*)d_in[15];
    const float* fb2 = (const float*)d_in[16];
    float* out = (float*)d_out;

    char* ws = (char*)d_ws;
    size_t o = 0;
    auto alloc = [&](size_t elems) -> void* {
        void* p = (void*)(ws + o);
        o += ((elems * 4 + 255) / 256) * 256;
        return p;
    };
    float* dinv   = (float*)alloc(NN);
    float* xd     = (float*)alloc(NN);
    int*   rowptr = (int*)alloc(NN + 1);
    unsigned long long* cnt64 = (unsigned long long*)alloc(2 * (size_t)NN);
    int*   bsum   = (int*)alloc(128);
    int2*  epair  = (int2*)alloc(2 * (size_t)EE);
    unsigned* Ga16 = (unsigned*)alloc((size_t)NN * 32);   // bf16 feature rows
    unsigned* Gb16 = (unsigned*)alloc((size_t)NN * 32);
    int*   slot   = (int*)alloc(EE);
    unsigned* Wf  = (unsigned*)alloc(4 * 4096);           // pre-packed W frags

    int gE  = (EE + 255) / 256;
    int nb  = (NN + 1023) / 1024;    // 98
    int gW4 = NN / 16;               // 6250: 4 waves x 4 nodes per block

    k_wpk<<<4, 256, 0, stream>>>(W3, W4, W5, fW1, Wf);
    hipMemsetAsync(cnt64, 0, NN * sizeof(unsigned long long), stream);
    k_count<<<gE, 256, 0, stream>>>(ei, ew, cnt64, slot);
    k_bsum<<<nb, 256, 0, stream>>>(cnt64, bsum);
    k_scan_out<<<nb, 256, 0, stream>>>(cnt64, bsum, x, rowptr, dinv, xd);
    k_fill<<<gE, 256, 0, stream>>>(ei, ew, slot, rowptr, epair);

    // Layer 1 (scalar gather + matvec) -> G2' bf16
    k_l1<<<gW4, 256, 0, stream>>>(xd, dinv, rowptr, epair, W1, b1, W2,
                                  (unsigned short*)Ga16);
    // Layers 2..4: fused quarter-gather + MFMA matvec
    k_gmv<<<gW4, 256, 0, stream>>>(Ga16, dinv, rowptr, epair, b2, Wf + 0,
                                   (unsigned short*)Gb16);
    k_gmv<<<gW4, 256, 0, stream>>>(Gb16, dinv, rowptr, epair, b3, Wf + 4096,
                                   (unsigned short*)Ga16);
    k_gmv<<<gW4, 256, 0, stream>>>(Ga16, dinv, rowptr, epair, b4, Wf + 8192,
                                   (unsigned short*)Gb16);
    // Layer 5 + head fused
    k_ghead<<<gW4, 256, 0, stream>>>(Gb16, dinv, rowptr, epair, b5, Wf + 12288,
                                     fb1, fW2, fb2, out);
}

// Round 7
// 366.997 us; speedup vs baseline: 1.1865x; 1.0890x over previous
//
#include <hip/hip_runtime.h>
#include <hip/hip_bf16.h>

#define NN 100000
#define EE 1250000

#define RL(x, l) __builtin_amdgcn_readlane((x), (l))
#define RLF(x, l) __int_as_float(__builtin_amdgcn_readlane(__float_as_int(x), (l)))

typedef __attribute__((ext_vector_type(8))) short v8s;
typedef __attribute__((ext_vector_type(4))) float v4f;
typedef __attribute__((ext_vector_type(4))) unsigned int v4u;

__device__ __forceinline__ unsigned short bf16rtn(float x) {
    unsigned u = __float_as_uint(x);
    unsigned r = u + 0x7fffu + ((u >> 16) & 1u);
    return (unsigned short)(r >> 16);
}
__device__ __forceinline__ unsigned bf16rtn2(float lo, float hi) {
    return (unsigned)bf16rtn(lo) | ((unsigned)bf16rtn(hi) << 16);
}
__device__ __forceinline__ float bflo(unsigned u) { return __uint_as_float(u << 16); }
__device__ __forceinline__ float bfhi(unsigned u) { return __uint_as_float(u & 0xffff0000u); }
__device__ __forceinline__ float bfs(unsigned short s) { return __uint_as_float((unsigned)s << 16); }

// ---------------- CSR build (packed; R9-proven) ----------------
// Atomic pass: ~23 G returning TRANSACTIONS/s fabric ceiling (R2/R5/R9/R10).
// R15: k_deg folded into the atomic — 64-bit packed add: hi dword = count
// (slot = old>>32), lo dword = sum(ew) in 2^-24 fixed point.

__global__ __launch_bounds__(256) void k_count(const int* __restrict__ ei,
                                               const float* __restrict__ ew,
                                               unsigned long long* __restrict__ cnt,
                                               int* __restrict__ slot) {
    int e = blockIdx.x * 256 + threadIdx.x;
    if (e >= EE) return;
    int d = __builtin_nontemporal_load(&ei[EE + e]);
    float w = __builtin_nontemporal_load(&ew[e]);
    unsigned fx = (unsigned)(w * 16777216.0f + 0.5f);   // w in [0,1] -> <= 2^24
    unsigned long long old =
        atomicAdd(&cnt[d], (1ULL << 32) | (unsigned long long)fx);
    __builtin_nontemporal_store((int)(old >> 32), &slot[e]);
}

__global__ __launch_bounds__(256) void k_bsum(const unsigned long long* __restrict__ cnt,
                                              int* __restrict__ bsum) {
    __shared__ int ls[256];
    int b = blockIdx.x, tid = threadIdx.x;
    int base = b * 1024 + tid * 4;
    int s = 0;
    #pragma unroll
    for (int j = 0; j < 4; ++j) { int g = base + j; if (g < NN) s += (int)(cnt[g] >> 32); }
    ls[tid] = s; __syncthreads();
    for (int off = 128; off > 0; off >>= 1) {
        if (tid < off) ls[tid] += ls[tid + off];
        __syncthreads();
    }
    if (tid == 0) bsum[b] = ls[0];
}

// per-1024 scan; block base computed in-kernel from bsum.
// R15: also emits dinv[n] = rsqrt(1 + sum ew) and xd[n] = dinv[n]*x[n].
__global__ __launch_bounds__(256) void k_scan_out(const unsigned long long* __restrict__ cnt,
                                                  const int* __restrict__ bsum,
                                                  const float* __restrict__ x,
                                                  int* __restrict__ rowptr,
                                                  float* __restrict__ dinv,
                                                  float* __restrict__ xd) {
    __shared__ int ls[256];
    __shared__ int sbase;
    int b = blockIdx.x, tid = threadIdx.x;
    if (tid < 64) {
        int w0 = (tid < b) ? bsum[tid] : 0;
        int w1 = ((64 + tid) < b) ? bsum[64 + tid] : 0;
        int s = w0 + w1;
        #pragma unroll
        for (int m = 32; m >= 1; m >>= 1) s += __shfl_xor(s, m, 64);
        if (tid == 0) sbase = s;
    }
    int base = b * 1024 + tid * 4;
    int c[4]; float sw[4]; int s = 0;
    #pragma unroll
    for (int j = 0; j < 4; ++j) {
        int g = base + j;
        unsigned long long v = (g < NN) ? cnt[g] : 0ULL;
        c[j] = (int)(v >> 32);
        sw[j] = (float)(unsigned)(v & 0xffffffffu) * (1.0f / 16777216.0f);
        s += c[j];
    }
    ls[tid] = s; __syncthreads();
    for (int off = 1; off < 256; off <<= 1) {
        int v = (tid >= off) ? ls[tid - off] : 0;
        __syncthreads();
        ls[tid] += v;
        __syncthreads();
    }
    int excl = ls[tid] - s + sbase;
    #pragma unroll
    for (int j = 0; j < 4; ++j) {
        int g = base + j;
        if (g < NN) {
            rowptr[g + 1] = excl + c[j];
            excl += c[j];
            float di = rsqrtf(sw[j] + 1.0f);
            dinv[g] = di;
            xd[g] = di * x[g];
        }
    }
    if (b == 0 && tid == 0) rowptr[0] = 0;
}

__global__ __launch_bounds__(256) void k_fill(const int* __restrict__ ei,
                                              const float* __restrict__ ew,
                                              const int* __restrict__ slot,
                                              const int* __restrict__ rowptr,
                                              int2* __restrict__ epair) {
    int e = blockIdx.x * 256 + threadIdx.x;
    if (e >= EE) return;
    int s = __builtin_nontemporal_load(&ei[e]);
    int d = __builtin_nontemporal_load(&ei[EE + e]);
    float w = __builtin_nontemporal_load(&ew[e]);
    int sl = __builtin_nontemporal_load(&slot[e]);
    int p = rowptr[d] + sl;
    epair[p] = make_int2(s, __float_as_int(w));
}

// ---------------- W pre-pack for MFMA (R12, R13-fixed) ----------------
// Packs a 64x64 row-major fp32 W into mfma_f32_16x16x32_bf16 B-fragment
// order, SPLIT hi+lo bf16 (Whi + Wlo reconstructs W to ~2^-17 rel => fp32-
// equivalent W precision; only the activation v carries bf16 rounding).
// Fragment (h, kt, nt): lane l holds 8 bf16 = W[kt*32 + (l>>4)*8 + j]
// [nt*16 + (l&15)], j=0..7, packed k-pairs per dword.  Group index
// g = (h*2+kt)*4+nt; dword addr = (g*64 + l)*4 + d.  16 KB per W.
// R13 BUGFIX: slot loop is 512 entries (i<2), NOT 1024.
// grid = 4 blocks: {W3, W4, W5, fW1}.
__global__ __launch_bounds__(256) void k_wpk(const float* __restrict__ Wa,
                                             const float* __restrict__ Wb,
                                             const float* __restrict__ Wc,
                                             const float* __restrict__ Wd,
                                             unsigned* __restrict__ Wf) {
    const float* W = (blockIdx.x == 0) ? Wa : (blockIdx.x == 1) ? Wb
                   : (blockIdx.x == 2) ? Wc : Wd;
    unsigned* out = Wf + blockIdx.x * 4096;
    int t = threadIdx.x;
    #pragma unroll
    for (int i = 0; i < 2; ++i) {
        int s = t * 2 + i;               // slot 0..511 = (kt*4+nt)*64 + lane
        int lane = s & 63;
        int nt = (s >> 6) & 3;
        int kt = s >> 8;                 // 0..1
        int col = nt * 16 + (lane & 15);
        int k0 = kt * 32 + (lane >> 4) * 8;
        unsigned hi[4], lo[4];
        #pragma unroll
        for (int d = 0; d < 4; ++d) {
            float w0 = W[(k0 + 2 * d) * 64 + col];
            float w1 = W[(k0 + 2 * d + 1) * 64 + col];
            unsigned short h0 = bf16rtn(w0), h1 = bf16rtn(w1);
            float r0 = w0 - bfs(h0), r1 = w1 - bfs(h1);
            hi[d] = (unsigned)h0 | ((unsigned)h1 << 16);
            lo[d] = (unsigned)bf16rtn(r0) | ((unsigned)bf16rtn(r1) << 16);
        }
        int gh = (0 * 2 + kt) * 4 + nt;  // 0..7
        int gl = (1 * 2 + kt) * 4 + nt;  // 8..15
        *(v4u*)&out[(gh * 64 + lane) * 4] = (v4u){hi[0], hi[1], hi[2], hi[3]};
        *(v4u*)&out[(gl * 64 + lane) * 4] = (v4u){lo[0], lo[1], lo[2], lo[3]};
    }
}

// ---------------- Eighth-wave gather (R17) ----------------
// R16 (quarter-wave, 32 rows in flight/wave) gave -12%; same lever, next
// notch: one node per 8-LANE group, lane owns 8 features via one uint4
// (16B) load per edge -> one load instr fetches 8 rows, 64 rows in flight
// per wave. Per-edge instr overhead halves. Per-feature fp32 accumulation
// order identical to R16 (self, then edges in CSR order).
__device__ __forceinline__ void gatherq8(
    const unsigned* __restrict__ G16, const int2* __restrict__ ep,
    int node, int beg, int end, int l8, float a[8])
{
    uint4 su = *(const uint4*)&G16[node * 32 + l8 * 4];
    a[0] = bflo(su.x); a[1] = bfhi(su.x);
    a[2] = bflo(su.y); a[3] = bfhi(su.y);
    a[4] = bflo(su.z); a[5] = bfhi(su.z);
    a[6] = bflo(su.w); a[7] = bfhi(su.w);
    int j = beg;
    for (; j + 8 <= end; j += 8) {            // full batch: 8 edges
        uint4 u[8]; float nv[8];
        #pragma unroll
        for (int t = 0; t < 8; ++t) {
            int2 p = ep[j + t];
            nv[t] = __int_as_float(p.y);
            u[t] = *(const uint4*)&G16[p.x * 32 + l8 * 4];
        }
        #pragma unroll
        for (int t = 0; t < 8; ++t) {
            a[0] = fmaf(bflo(u[t].x), nv[t], a[0]);
            a[1] = fmaf(bfhi(u[t].x), nv[t], a[1]);
            a[2] = fmaf(bflo(u[t].y), nv[t], a[2]);
            a[3] = fmaf(bfhi(u[t].y), nv[t], a[3]);
            a[4] = fmaf(bflo(u[t].z), nv[t], a[4]);
            a[5] = fmaf(bfhi(u[t].z), nv[t], a[5]);
            a[6] = fmaf(bflo(u[t].w), nv[t], a[6]);
            a[7] = fmaf(bfhi(u[t].w), nv[t], a[7]);
        }
    }
    if (j < end) {                            // masked tail 1..7
        uint4 u[8]; float nv[8];
        #pragma unroll
        for (int t = 0; t < 8; ++t) {
            int idx = j + t;
            int2 p = ep[idx < end ? idx : j];
            nv[t] = (idx < end) ? __int_as_float(p.y) : 0.f;
            u[t] = *(const uint4*)&G16[p.x * 32 + l8 * 4];
        }
        #pragma unroll
        for (int t = 0; t < 8; ++t) {
            a[0] = fmaf(bflo(u[t].x), nv[t], a[0]);
            a[1] = fmaf(bfhi(u[t].x), nv[t], a[1]);
            a[2] = fmaf(bflo(u[t].y), nv[t], a[2]);
            a[3] = fmaf(bfhi(u[t].y), nv[t], a[3]);
            a[4] = fmaf(bflo(u[t].z), nv[t], a[4]);
            a[5] = fmaf(bfhi(u[t].z), nv[t], a[5]);
            a[6] = fmaf(bflo(u[t].w), nv[t], a[6]);
            a[7] = fmaf(bfhi(u[t].w), nv[t], a[7]);
        }
    }
}

// ---------------- Layers ----------------
// Identity: Agg_l[d] = dinv_d * ( G'_l[d] + sum_e w_e * G'_l[src] ), G' = dinv (.) G.
// G' stored bf16 (rows = 32 uints = 128 B). All accumulation fp32.
// R12/R13: matvec on the MFMA pipe. R17: 8 nodes/wave = MFMA A rows 0-7
// (rows 8-15 dup via rr=lane&7, outputs ignored); C rows 4-7 live in
// lanes 16-31 per the verified C/D mapping.

// Layer 1: z scalar agg + matvec, W2 via LDS. grid NN/16.
__global__ __launch_bounds__(256) void k_l1(
    const float* __restrict__ xd, const float* __restrict__ dinv,
    const int* __restrict__ rowptr, const int2* __restrict__ ep,
    const float* __restrict__ W1, const float* __restrict__ b1,
    const float* __restrict__ W2, unsigned short* __restrict__ Gout)
{
    __shared__ float sW[4096];
    int tid = threadIdx.x;
    #pragma unroll
    for (int i = 0; i < 16; ++i) sW[tid + i * 256] = W2[tid + i * 256];
    __syncthreads();
    int lane = tid & 63, l16 = lane & 15, sub = lane >> 4;
    int g4 = blockIdx.x * 4 + (tid >> 6);
    int nodeS = g4 * 4 + sub;
    int beg = rowptr[nodeS], end = rowptr[nodeS + 1];
    float partial = 0.f;
    for (int idx = beg + l16; idx < end; idx += 16) {
        int2 p = ep[idx];
        partial = fmaf(__int_as_float(p.y), xd[p.x], partial);
    }
    #pragma unroll
    for (int m = 8; m >= 1; m >>= 1) partial += __shfl_xor(partial, m, 64);
    float z = dinv[nodeS] * (xd[nodeS] + partial);   // valid where l16==0
    float z0 = RLF(z, 0), z1 = RLF(z, 16), z2 = RLF(z, 32), z3 = RLF(z, 48);
    float w1l = W1[lane], b1l = b1[lane];
    float v0 = fmaxf(fmaf(z0, w1l, b1l), 0.f);
    float v1 = fmaxf(fmaf(z1, w1l, b1l), 0.f);
    float v2 = fmaxf(fmaf(z2, w1l, b1l), 0.f);
    float v3 = fmaxf(fmaf(z3, w1l, b1l), 0.f);
    float a0 = 0.f, a1 = 0.f, a2 = 0.f, a3 = 0.f;
    #pragma unroll
    for (int k = 0; k < 64; ++k) {
        float wk = sW[k * 64 + lane];
        a0 = fmaf(RLF(v0, k), wk, a0);
        a1 = fmaf(RLF(v1, k), wk, a1);
        a2 = fmaf(RLF(v2, k), wk, a2);
        a3 = fmaf(RLF(v3, k), wk, a3);
    }
    int n0 = g4 * 4;
    Gout[(n0 + 0) * 64 + lane] = bf16rtn(dinv[n0 + 0] * a0);
    Gout[(n0 + 1) * 64 + lane] = bf16rtn(dinv[n0 + 1] * a1);
    Gout[(n0 + 2) * 64 + lane] = bf16rtn(dinv[n0 + 2] * a2);
    Gout[(n0 + 3) * 64 + lane] = bf16rtn(dinv[n0 + 3] * a3);
}

// Fused eighth-wave gather + bias/relu + MFMA matvec + dinv scale
// (layers 2..4). 8 nodes/wave; grid = NN/32.
__global__ __launch_bounds__(256) void k_gmv(
    const unsigned* __restrict__ G16, const float* __restrict__ dinv,
    const int* __restrict__ rowptr, const int2* __restrict__ ep,
    const float* __restrict__ bias, const unsigned* __restrict__ Wf,
    unsigned short* __restrict__ Gout)
{
    __shared__ __align__(16) unsigned sB[4096];   // 16 KB: Whi/Wlo fragments
    __shared__ __align__(16) unsigned sA[4][256]; // per-wave A scratch (8n x 32dw)
    int tid = threadIdx.x;
    #pragma unroll
    for (int i = 0; i < 4; ++i)
        ((v4u*)sB)[tid + i * 256] = ((const v4u*)Wf)[tid + i * 256];
    int lane = tid & 63;
    int wid  = tid >> 6;
    int q    = lane >> 3;                         // node slot 0..7
    int l8   = lane & 7;
    int n0 = (blockIdx.x * 4 + wid) * 8;
    int node = n0 + q;
    int beg = rowptr[node], end = rowptr[node + 1];
    float a[8];
    gatherq8(G16, ep, node, beg, end, l8, a);
    float din = dinv[node];
    float4 bv0 = ((const float4*)bias)[l8 * 2];   // features 8*l8..+3
    float4 bv1 = ((const float4*)bias)[l8 * 2 + 1];
    float v0 = fmaxf(fmaf(din, a[0], bv0.x), 0.f);
    float v1 = fmaxf(fmaf(din, a[1], bv0.y), 0.f);
    float v2 = fmaxf(fmaf(din, a[2], bv0.z), 0.f);
    float v3 = fmaxf(fmaf(din, a[3], bv0.w), 0.f);
    float v4 = fmaxf(fmaf(din, a[4], bv1.x), 0.f);
    float v5 = fmaxf(fmaf(din, a[5], bv1.y), 0.f);
    float v6 = fmaxf(fmaf(din, a[6], bv1.z), 0.f);
    float v7 = fmaxf(fmaf(din, a[7], bv1.w), 0.f);
    *(uint4*)&sA[wid][q * 32 + l8 * 4] = make_uint4(
        bf16rtn2(v0, v1), bf16rtn2(v2, v3),
        bf16rtn2(v4, v5), bf16rtn2(v6, v7));      // k-pairs (8l8..8l8+7)
    __syncthreads();                              // sB ready (sA wave-local)
    // ---- matvec on MFMA pipe (A rows 0-7 = nodes; 8-15 dup) ----
    int rr  = lane & 7;
    int blk = lane >> 4;
    v8s fa0 = *(const v8s*)&sA[wid][rr * 32 +  0 + blk * 4];   // kt=0
    v8s fa1 = *(const v8s*)&sA[wid][rr * 32 + 16 + blk * 4];   // kt=1
    v4f acc[4];
    #pragma unroll
    for (int nt = 0; nt < 4; ++nt) {
        v8s bh0 = *(const v8s*)&sB[((0 * 4 + nt) * 64 + lane) * 4];  // h=0 kt=0
        v8s bh1 = *(const v8s*)&sB[((1 * 4 + nt) * 64 + lane) * 4];  // h=0 kt=1
        v8s bl0 = *(const v8s*)&sB[((2 * 4 + nt) * 64 + lane) * 4];  // h=1 kt=0
        v8s bl1 = *(const v8s*)&sB[((3 * 4 + nt) * 64 + lane) * 4];  // h=1 kt=1
        v4f c = {0.f, 0.f, 0.f, 0.f};
        c = __builtin_amdgcn_mfma_f32_16x16x32_bf16(fa0, bl0, c, 0, 0, 0);
        c = __builtin_amdgcn_mfma_f32_16x16x32_bf16(fa1, bl1, c, 0, 0, 0);
        c = __builtin_amdgcn_mfma_f32_16x16x32_bf16(fa0, bh0, c, 0, 0, 0);
        c = __builtin_amdgcn_mfma_f32_16x16x32_bf16(fa1, bh1, c, 0, 0, 0);
        acc[nt] = c;
    }
    // C: col = lane&15, row = (lane>>4)*4 + reg. Rows 0-3 -> lanes 0-15,
    // rows 4-7 -> lanes 16-31 (rows 8-15 = dup, lanes 32-63 idle here).
    int grp = lane >> 4;
    int l16 = lane & 15;
    if (grp < 2) {
        int rb = grp * 4;
        float4 dn = *(const float4*)&dinv[n0 + rb];
        #pragma unroll
        for (int r = 0; r < 4; ++r) {
            float d = (r == 0) ? dn.x : (r == 1) ? dn.y : (r == 2) ? dn.z : dn.w;
            #pragma unroll
            for (int nt = 0; nt < 4; ++nt)
                Gout[(n0 + rb + r) * 64 + nt * 16 + l16] = bf16rtn(d * acc[nt][r]);
        }
    }
}

// Fused eighth-wave gather + layer-5 bias/relu + head (fW1 MFMA, relu,
// fW2 dot). 8 nodes/wave; grid = NN/32.
__global__ __launch_bounds__(256) void k_ghead(
    const unsigned* __restrict__ G16, const float* __restrict__ dinv,
    const int* __restrict__ rowptr, const int2* __restrict__ ep,
    const float* __restrict__ b5, const unsigned* __restrict__ Wf,
    const float* __restrict__ fb1, const float* __restrict__ fW2,
    const float* __restrict__ fb2, float* __restrict__ out)
{
    __shared__ __align__(16) unsigned sB[4096];
    __shared__ __align__(16) unsigned sA[4][256];
    int tid = threadIdx.x;
    #pragma unroll
    for (int i = 0; i < 4; ++i)
        ((v4u*)sB)[tid + i * 256] = ((const v4u*)Wf)[tid + i * 256];
    int lane = tid & 63;
    int wid  = tid >> 6;
    int q    = lane >> 3;
    int l8   = lane & 7;
    int l16  = lane & 15;
    int n0 = (blockIdx.x * 4 + wid) * 8;
    int node = n0 + q;
    float fb1v[4], fw2v[4];
    #pragma unroll
    for (int nt = 0; nt < 4; ++nt) {
        fb1v[nt] = fb1[nt * 16 + l16];
        fw2v[nt] = fW2[nt * 16 + l16];
    }
    float fb2s = fb2[0];
    int beg = rowptr[node], end = rowptr[node + 1];
    float a[8];
    gatherq8(G16, ep, node, beg, end, l8, a);
    float din = dinv[node];
    float4 bv0 = ((const float4*)b5)[l8 * 2];
    float4 bv1 = ((const float4*)b5)[l8 * 2 + 1];
    float v0 = fmaxf(fmaf(din, a[0], bv0.x), 0.f);
    float v1 = fmaxf(fmaf(din, a[1], bv0.y), 0.f);
    float v2 = fmaxf(fmaf(din, a[2], bv0.z), 0.f);
    float v3 = fmaxf(fmaf(din, a[3], bv0.w), 0.f);
    float v4 = fmaxf(fmaf(din, a[4], bv1.x), 0.f);
    float v5 = fmaxf(fmaf(din, a[5], bv1.y), 0.f);
    float v6 = fmaxf(fmaf(din, a[6], bv1.z), 0.f);
    float v7 = fmaxf(fmaf(din, a[7], bv1.w), 0.f);
    *(uint4*)&sA[wid][q * 32 + l8 * 4] = make_uint4(
        bf16rtn2(v0, v1), bf16rtn2(v2, v3),
        bf16rtn2(v4, v5), bf16rtn2(v6, v7));
    __syncthreads();
    int rr  = lane & 7;
    int blk = lane >> 4;
    v8s fa0 = *(const v8s*)&sA[wid][rr * 32 +  0 + blk * 4];
    v8s fa1 = *(const v8s*)&sA[wid][rr * 32 + 16 + blk * 4];
    v4f acc[4];
    #pragma unroll
    for (int nt = 0; nt < 4; ++nt) {
        v8s bh0 = *(const v8s*)&sB[((0 * 4 + nt) * 64 + lane) * 4];
        v8s bh1 = *(const v8s*)&sB[((1 * 4 + nt) * 64 + lane) * 4];
        v8s bl0 = *(const v8s*)&sB[((2 * 4 + nt) * 64 + lane) * 4];
        v8s bl1 = *(const v8s*)&sB[((3 * 4 + nt) * 64 + lane) * 4];
        v4f c = {0.f, 0.f, 0.f, 0.f};
        c = __builtin_amdgcn_mfma_f32_16x16x32_bf16(fa0, bl0, c, 0, 0, 0);
        c = __builtin_amdgcn_mfma_f32_16x16x32_bf16(fa1, bl1, c, 0, 0, 0);
        c = __builtin_amdgcn_mfma_f32_16x16x32_bf16(fa0, bh0, c, 0, 0, 0);
        c = __builtin_amdgcn_mfma_f32_16x16x32_bf16(fa1, bh1, c, 0, 0, 0);
        acc[nt] = c;
    }
    // lanes 0-15: nodes n0+0..3 (regs 0-3); lanes 16-31: nodes n0+4..7.
    float tr[4];
    #pragma unroll
    for (int r = 0; r < 4; ++r) {
        float t = 0.f;
        #pragma unroll
        for (int nt = 0; nt < 4; ++nt)
            t += fmaxf(acc[nt][r] + fb1v[nt], 0.f) * fw2v[nt];
        #pragma unroll
        for (int m = 8; m >= 1; m >>= 1) t += __shfl_xor(t, m, 64);
        tr[r] = t;
    }
    if (lane == 0) {
        float4 o = {tr[0] + fb2s, tr[1] + fb2s, tr[2] + fb2s, tr[3] + fb2s};
        *(float4*)&out[n0] = o;
    } else if (lane == 16) {
        float4 o = {tr[0] + fb2s, tr[1] + fb2s, tr[2] + fb2s, tr[3] + fb2s};
        *(float4*)&out[n0 + 4] = o;
    }
}

// ---------------- Launch ----------------

extern "C" void kernel_launch(void* const* d_in, const int* in_sizes, int n_in,
                              void* d_out, int out_size, void* d_ws, size_t ws_size,
                              hipStream_t stream) {
    const float* x   = (const float*)d_in[0];
    const int*   ei  = (const int*)d_in[1];
    const float* ew  = (const float*)d_in[2];
    const float* W1  = (const float*)d_in[3];
    const float* b1  = (const float*)d_in[4];
    const float* W2  = (const float*)d_in[5];
    const float* b2  = (const float*)d_in[6];
    const float* W3  = (const float*)d_in[7];
    const float* b3  = (const float*)d_in[8];
    const float* W4  = (const float*)d_in[9];
    const float* b4  = (const float*)d_in[10];
    const float* W5  = (const float*)d_in[11];
    const float* b5  = (const float*)d_in[12];
    const float* fW1 = (const float*)d_in[13];
    const float* fb1 = (const float*)d_in[14];
    const float* fW2 = (const float*)d_in[15];
    const float* fb2 = (const float*)d_in[16];
    float* out = (float*)d_out;

    char* ws = (char*)d_ws;
    size_t o = 0;
    auto alloc = [&](size_t elems) -> void* {
        void* p = (void*)(ws + o);
        o += ((elems * 4 + 255) / 256) * 256;
        return p;
    };
    float* dinv   = (float*)alloc(NN);
    float* xd     = (float*)alloc(NN);
    int*   rowptr = (int*)alloc(NN + 1);
    unsigned long long* cnt64 = (unsigned long long*)alloc(2 * (size_t)NN);
    int*   bsum   = (int*)alloc(128);
    int2*  epair  = (int2*)alloc(2 * (size_t)EE);
    unsigned* Ga16 = (unsigned*)alloc((size_t)NN * 32);   // bf16 feature rows
    unsigned* Gb16 = (unsigned*)alloc((size_t)NN * 32);
    int*   slot   = (int*)alloc(EE);
    unsigned* Wf  = (unsigned*)alloc(4 * 4096);           // pre-packed W frags

    int gE  = (EE + 255) / 256;
    int nb  = (NN + 1023) / 1024;    // 98
    int gW4 = NN / 16;               // 6250: k_l1 (4 nodes/wave)
    int gW8 = NN / 32;               // 3125: 4 waves x 8 nodes per block

    k_wpk<<<4, 256, 0, stream>>>(W3, W4, W5, fW1, Wf);
    hipMemsetAsync(cnt64, 0, NN * sizeof(unsigned long long), stream);
    k_count<<<gE, 256, 0, stream>>>(ei, ew, cnt64, slot);
    k_bsum<<<nb, 256, 0, stream>>>(cnt64, bsum);
    k_scan_out<<<nb, 256, 0, stream>>>(cnt64, bsum, x, rowptr, dinv, xd);
    k_fill<<<gE, 256, 0, stream>>>(ei, ew, slot, rowptr, epair);

    // Layer 1 (scalar gather + matvec) -> G2' bf16
    k_l1<<<gW4, 256, 0, stream>>>(xd, dinv, rowptr, epair, W1, b1, W2,
                                  (unsigned short*)Ga16);
    // Layers 2..4: fused eighth-wave gather + MFMA matvec
    k_gmv<<<gW8, 256, 0, stream>>>(Ga16, dinv, rowptr, epair, b2, Wf + 0,
                                   (unsigned short*)Gb16);
    k_gmv<<<gW8, 256, 0, stream>>>(Gb16, dinv, rowptr, epair, b3, Wf + 4096,
                                   (unsigned short*)Ga16);
    k_gmv<<<gW8, 256, 0, stream>>>(Ga16, dinv, rowptr, epair, b4, Wf + 8192,
                                   (unsigned short*)Gb16);
    // Layer 5 + head fused
    k_ghead<<<gW8, 256, 0, stream>>>(Gb16, dinv, rowptr, epair, b5, Wf + 12288,
                                     fb1, fW2, fb2, out);
}